// Round 18
// baseline (308.199 us; speedup 1.0000x reference)
//
#include <hip/hip_runtime.h>
#include <math.h>

#define NN 100000
#define NE 1600000
#define DF 256
#define HH 64
#define TT 4
#define GG 8
#define BN_EPS 1e-5f
#define NTOT (NE + NN)               // srcl entries incl. self-loops

#define BROWS 512                    // rows per bucket
#define NBK ((NN + BROWS - 1) / BROWS)   // 196
#define BCAP 10240                   // bucket capacity (mean 8192, sigma 90)
#define PCHUNK 1600
#define NPB (NE / PCHUNK)            // 1000

typedef __attribute__((ext_vector_type(8))) short short8v;
typedef __attribute__((ext_vector_type(4))) float f32x4;
typedef unsigned short ushort_t;
typedef unsigned char uchar_t;
typedef unsigned int uint_t;

__device__ __forceinline__ void atomicMaxF(float* addr, float val) {
  if (val >= 0.f) atomicMax((int*)addr, __float_as_int(val));
  else            atomicMin((unsigned int*)addr, __float_as_uint(val));
}

__device__ __forceinline__ short f2bf(float f) {
  uint_t u = __float_as_uint(f);
  u += 0x7FFFu + ((u >> 16) & 1u);
  return (short)(u >> 16);
}
__device__ __forceinline__ float bf2f(uint_t u) { return __uint_as_float(u << 16); }
__device__ __forceinline__ float bfhi(uint_t u) { return __uint_as_float(u & 0xFFFF0000u); }

// ---------------- setup: W->bf16, stats=0, maxb=-inf, Bcnt=0 ----------------
__global__ void k_setup(const float* __restrict__ Wf, ushort_t* __restrict__ Wbf,
                        const float* __restrict__ Wc, ushort_t* __restrict__ Wbf2,
                        float* __restrict__ stats, float* __restrict__ maxb,
                        int* __restrict__ Bcnt) {
  int i = blockIdx.x * 256 + threadIdx.x;       // 80 blocks x 256 = 20480
  if (i < DF * HH) Wbf[i] = (ushort_t)f2bf(Wf[i]);
  else {
    int j = i - DF * HH;
    if (j < HH * HH) Wbf2[j] = (ushort_t)f2bf(Wc[j]);
  }
  if (i < 512) stats[i] = 0.f;
  if (i < 64)  maxb[i]  = -INFINITY;
  if (i < NBK) Bcnt[i]  = 0;
}

// ---------------- GEMM1 (MFMA bf16): h1 = x @ W_first + b (bf16 out), + BN stats ----
__global__ __launch_bounds__(256, 2) void k_gemm1_mfma(
    const float* __restrict__ x, const ushort_t* __restrict__ Wbf,
    const float* __restrict__ b, ushort_t* __restrict__ h1,
    float* __restrict__ stats) {
  const int lane = threadIdx.x & 63;
  const int li = lane & 15;
  const int lh = lane >> 4;
  const int gw = (blockIdx.x * 256 + (int)threadIdx.x) >> 6;
  const int nw = (gridDim.x * 256) >> 6;

  short8v bf[8][4];
#pragma unroll
  for (int s = 0; s < 8; ++s)
#pragma unroll
    for (int ct = 0; ct < 4; ++ct)
#pragma unroll
      for (int e = 0; e < 8; ++e)
        bf[s][ct][e] = (short)Wbf[(32 * s + 8 * lh + e) * HH + ct * 16 + li];

  float bias[4];
#pragma unroll
  for (int ct = 0; ct < 4; ++ct) bias[ct] = b[ct * 16 + li];

  float ps[4] = {0.f, 0.f, 0.f, 0.f}, pss[4] = {0.f, 0.f, 0.f, 0.f};

  for (int t = gw; t < NN / 16; t += nw) {
    const float* xb = x + (size_t)(t * 16 + li) * DF + 8 * lh;
    f32x4 acc[4];
#pragma unroll
    for (int ct = 0; ct < 4; ++ct) acc[ct] = (f32x4){0.f, 0.f, 0.f, 0.f};

#pragma unroll
    for (int s = 0; s < 8; ++s) {
      float4 a0 = *(const float4*)(xb + 32 * s);
      float4 a1 = *(const float4*)(xb + 32 * s + 4);
      short8v af;
      af[0] = f2bf(a0.x); af[1] = f2bf(a0.y); af[2] = f2bf(a0.z); af[3] = f2bf(a0.w);
      af[4] = f2bf(a1.x); af[5] = f2bf(a1.y); af[6] = f2bf(a1.z); af[7] = f2bf(a1.w);
#pragma unroll
      for (int ct = 0; ct < 4; ++ct)
        acc[ct] = __builtin_amdgcn_mfma_f32_16x16x32_bf16(af, bf[s][ct], acc[ct], 0, 0, 0);
    }

    ushort_t* hb = h1 + (size_t)t * 16 * HH;
#pragma unroll
    for (int ct = 0; ct < 4; ++ct) {
#pragma unroll
      for (int r = 0; r < 4; ++r) {
        float h = acc[ct][r] + bias[ct];
        hb[(lh * 4 + r) * HH + ct * 16 + li] = (ushort_t)f2bf(h);
        ps[ct] += h; pss[ct] += h * h;
      }
    }
  }

#pragma unroll
  for (int ct = 0; ct < 4; ++ct) {
    ps[ct]  += __shfl_xor(ps[ct], 16);  ps[ct]  += __shfl_xor(ps[ct], 32);
    pss[ct] += __shfl_xor(pss[ct], 16); pss[ct] += __shfl_xor(pss[ct], 32);
  }
  if (lane < 16) {
#pragma unroll
    for (int ct = 0; ct < 4; ++ct) {
      atomicAdd(&stats[ct * 16 + lane], ps[ct]);
      atomicAdd(&stats[HH + ct * 16 + lane], pss[ct]);
    }
  }
}

// ---------------- fused: BN-finalize + normalize(h1)+ReLU; np0 + pool via 5th
//                  MFMA tile; g = f @ W_conv (bf16 out) ----------------
__global__ __launch_bounds__(256) void k_norm_gemm2(
    const ushort_t* __restrict__ h1, const float* __restrict__ stats,
    const float* __restrict__ gamma, const float* __restrict__ beta,
    const float* __restrict__ Wl0, const float* __restrict__ bl0,
    const int* __restrict__ batch, const ushort_t* __restrict__ Wbf2,
    float* __restrict__ node_pred, float* __restrict__ maxbuf,
    ushort_t* __restrict__ g) {
  __shared__ float lmax[GG * TT];
  __shared__ float abl[128];
  if (threadIdx.x < GG * TT) lmax[threadIdx.x] = -INFINITY;
  if (threadIdx.x < 64) {
    int c = threadIdx.x;
    float mu  = stats[c] * (1.f / NN);
    float var = stats[HH + c] * (1.f / NN) - mu * mu;
    float a = gamma[c] * rsqrtf(var + BN_EPS);
    abl[c] = a;
    abl[HH + c] = beta[c] - mu * a;
  }
  __syncthreads();

  const int lane = threadIdx.x & 63;
  const int li = lane & 15;
  const int lh = lane >> 4;
  const int gw = (blockIdx.x * 256 + (int)threadIdx.x) >> 6;
  const int nw = (gridDim.x * 256) >> 6;

  short8v bfr[2][4];
#pragma unroll
  for (int s = 0; s < 2; ++s)
#pragma unroll
    for (int ct = 0; ct < 4; ++ct)
#pragma unroll
      for (int e = 0; e < 8; ++e)
        bfr[s][ct][e] = (short)Wbf2[(32 * s + 8 * lh + e) * HH + ct * 16 + li];

  short8v bhd[2];
#pragma unroll
  for (int s = 0; s < 2; ++s)
#pragma unroll
    for (int e = 0; e < 8; ++e)
      bhd[s][e] = (li < TT) ? f2bf(Wl0[(32 * s + 8 * lh + e) * TT + li]) : (short)0;

  const float4 sa0 = *(const float4*)(abl + 8 * lh);
  const float4 sa1 = *(const float4*)(abl + 8 * lh + 4);
  const float4 sb0 = *(const float4*)(abl + HH + 8 * lh);
  const float4 sb1 = *(const float4*)(abl + HH + 8 * lh + 4);
  const float4 ta0 = *(const float4*)(abl + 32 + 8 * lh);
  const float4 ta1 = *(const float4*)(abl + 32 + 8 * lh + 4);
  const float4 tb0 = *(const float4*)(abl + HH + 32 + 8 * lh);
  const float4 tb1 = *(const float4*)(abl + HH + 32 + 8 * lh + 4);
  const float blv = (li < TT) ? bl0[li] : 0.f;

  for (int t = gw; t < NN / 16; t += nw) {
    const ushort_t* hb = h1 + (size_t)(t * 16 + li) * HH + 8 * lh;
    uint4 xa = *(const uint4*)(hb);
    uint4 xc = *(const uint4*)(hb + 32);

    short8v af0, af1;
    af0[0] = f2bf(fmaxf(fmaf(sa0.x, bf2f(xa.x), sb0.x), 0.f));
    af0[1] = f2bf(fmaxf(fmaf(sa0.y, bfhi(xa.x), sb0.y), 0.f));
    af0[2] = f2bf(fmaxf(fmaf(sa0.z, bf2f(xa.y), sb0.z), 0.f));
    af0[3] = f2bf(fmaxf(fmaf(sa0.w, bfhi(xa.y), sb0.w), 0.f));
    af0[4] = f2bf(fmaxf(fmaf(sa1.x, bf2f(xa.z), sb1.x), 0.f));
    af0[5] = f2bf(fmaxf(fmaf(sa1.y, bfhi(xa.z), sb1.y), 0.f));
    af0[6] = f2bf(fmaxf(fmaf(sa1.z, bf2f(xa.w), sb1.z), 0.f));
    af0[7] = f2bf(fmaxf(fmaf(sa1.w, bfhi(xa.w), sb1.w), 0.f));
    af1[0] = f2bf(fmaxf(fmaf(ta0.x, bf2f(xc.x), tb0.x), 0.f));
    af1[1] = f2bf(fmaxf(fmaf(ta0.y, bfhi(xc.x), tb0.y), 0.f));
    af1[2] = f2bf(fmaxf(fmaf(ta0.z, bf2f(xc.y), tb0.z), 0.f));
    af1[3] = f2bf(fmaxf(fmaf(ta0.w, bfhi(xc.y), tb0.w), 0.f));
    af1[4] = f2bf(fmaxf(fmaf(ta1.x, bf2f(xc.z), tb1.x), 0.f));
    af1[5] = f2bf(fmaxf(fmaf(ta1.y, bfhi(xc.z), tb1.y), 0.f));
    af1[6] = f2bf(fmaxf(fmaf(ta1.z, bf2f(xc.w), tb1.z), 0.f));
    af1[7] = f2bf(fmaxf(fmaf(ta1.w, bfhi(xc.w), tb1.w), 0.f));

    f32x4 acc[4], acch;
#pragma unroll
    for (int ct = 0; ct < 4; ++ct) {
      acc[ct] = (f32x4){0.f, 0.f, 0.f, 0.f};
      acc[ct] = __builtin_amdgcn_mfma_f32_16x16x32_bf16(af0, bfr[0][ct], acc[ct], 0, 0, 0);
      acc[ct] = __builtin_amdgcn_mfma_f32_16x16x32_bf16(af1, bfr[1][ct], acc[ct], 0, 0, 0);
    }
    acch = (f32x4){0.f, 0.f, 0.f, 0.f};
    acch = __builtin_amdgcn_mfma_f32_16x16x32_bf16(af0, bhd[0], acch, 0, 0, 0);
    acch = __builtin_amdgcn_mfma_f32_16x16x32_bf16(af1, bhd[1], acch, 0, 0, 0);

    ushort_t* gb = g + (size_t)t * 16 * HH;
#pragma unroll
    for (int ct = 0; ct < 4; ++ct)
#pragma unroll
      for (int r = 0; r < 4; ++r)
        gb[(lh * 4 + r) * HH + ct * 16 + li] = (ushort_t)f2bf(acc[ct][r]);

    if (li < TT) {
#pragma unroll
      for (int r = 0; r < 4; ++r) {
        int row = t * 16 + lh * 4 + r;
        float np = acch[r] + blv;
        atomicMaxF(&lmax[batch[row] * TT + li], np);
        node_pred[(size_t)row * TT + li] = np;
      }
    }
  }
  __syncthreads();
  if (threadIdx.x < GG * TT) atomicMaxF(&maxbuf[threadIdx.x], lmax[threadIdx.x]);
}

// ---------------- fused: BN-finalize + normalize+ReLU + head + max-pool ----
__global__ __launch_bounds__(256) void k_norm_np(
    const ushort_t* __restrict__ hin, const float* __restrict__ stats,
    const float* __restrict__ gamma, const float* __restrict__ beta,
    const float* __restrict__ Wlin, const float* __restrict__ blin,
    const int* __restrict__ batch, float* __restrict__ node_pred,
    float* __restrict__ maxbuf, int rpb) {
  __shared__ float lmax[GG * TT];
  __shared__ float abl[128];
  if (threadIdx.x < GG * TT) lmax[threadIdx.x] = -INFINITY;
  if (threadIdx.x < 64) {
    int c = threadIdx.x;
    float mu  = stats[c] * (1.f / NN);
    float var = stats[HH + c] * (1.f / NN) - mu * mu;
    float a = gamma[c] * rsqrtf(var + BN_EPS);
    abl[c] = a;
    abl[HH + c] = beta[c] - mu * a;
  }
  __syncthreads();

  const int lane = threadIdx.x & 63;
  const int wid  = threadIdx.x >> 6;
  const float a  = abl[lane];
  const float b2 = abl[HH + lane];
  const float4 w = ((const float4*)Wlin)[lane];
  const float4 bl = *(const float4*)blin;
  int r0 = blockIdx.x * rpb;
  int r1 = min(r0 + rpb, NN);

  for (int r = r0 + wid; r < r1; r += 4) {
    float h = bf2f(hin[(size_t)r * HH + lane]);
    float f = fmaxf(fmaf(a, h, b2), 0.f);
    float p0 = f * w.x, p1 = f * w.y, p2 = f * w.z, p3 = f * w.w;
#pragma unroll
    for (int off = 32; off; off >>= 1) {
      p0 += __shfl_xor(p0, off);
      p1 += __shfl_xor(p1, off);
      p2 += __shfl_xor(p2, off);
      p3 += __shfl_xor(p3, off);
    }
    if (lane == 0) {
      float4 np;
      np.x = p0 + bl.x; np.y = p1 + bl.y; np.z = p2 + bl.z; np.w = p3 + bl.w;
      int g = batch[r];
      atomicMaxF(&lmax[g * TT + 0], np.x);
      atomicMaxF(&lmax[g * TT + 1], np.y);
      atomicMaxF(&lmax[g * TT + 2], np.z);
      atomicMaxF(&lmax[g * TT + 3], np.w);
      float4* op = (float4*)(node_pred + (size_t)r * TT);
      float4 o = *op;
      np.x += o.x; np.y += o.y; np.z += o.z; np.w += o.w;
      *op = np;
    }
  }
  __syncthreads();
  if (threadIdx.x < GG * TT) atomicMaxF(&maxbuf[threadIdx.x], lmax[threadIdx.x]);
}

// ---------------- bucketed CSR build ----------------
__global__ __launch_bounds__(256) void k_part(
    const int* __restrict__ ei, int* __restrict__ Bcnt,
    uint2* __restrict__ ebuf) {
  __shared__ int hist[256], start[256], cnt[256], gbase[256];
  __shared__ int ssrc[PCHUNK], sdst[PCHUNK];
  const int t = threadIdx.x;
  hist[t] = 0; cnt[t] = 0;
  __syncthreads();
  const int e0 = blockIdx.x * PCHUNK;
  for (int i = t; i < PCHUNK; i += 256)
    atomicAdd(&hist[ei[NE + e0 + i] >> 9], 1);
  __syncthreads();
  int v = hist[t];
  start[t] = v;
  __syncthreads();
  for (int off = 1; off < 256; off <<= 1) {
    int u = (t >= off) ? start[t - off] : 0;
    __syncthreads();
    start[t] += u;
    __syncthreads();
  }
  int incl = start[t];
  __syncthreads();
  start[t] = incl - v;                       // exclusive
  if (v > 0) gbase[t] = atomicAdd(&Bcnt[t], v);
  __syncthreads();
  for (int i = t; i < PCHUNK; i += 256) {
    int src = ei[e0 + i];
    int dst = ei[NE + e0 + i];
    int b = dst >> 9;
    int p = start[b] + atomicAdd(&cnt[b], 1);
    ssrc[p] = src; sdst[p] = dst;
  }
  __syncthreads();
  for (int i = t; i < PCHUNK; i += 256) {
    int dst = sdst[i];
    int b = dst >> 9;
    uint2 pr; pr.x = (uint_t)ssrc[i]; pr.y = (uint_t)dst;
    ebuf[(size_t)b * BCAP + gbase[b] + (i - start[b])] = pr;
  }
}

__global__ void k_bscan(const int* __restrict__ Bcnt, int* __restrict__ Bbase) {
  __shared__ int s[256];
  int t = threadIdx.x;
  int v = 0;
  if (t < NBK) {
    int rows = min(BROWS, NN - t * BROWS);
    v = Bcnt[t] + rows;
  }
  s[t] = v;
  __syncthreads();
  for (int off = 1; off < 256; off <<= 1) {
    int u = (t >= off) ? s[t - off] : 0;
    __syncthreads();
    s[t] += u;
    __syncthreads();
  }
  if (t < NBK) Bbase[t] = s[t] - v;
}

__global__ __launch_bounds__(256) void k_fill2(
    const int* __restrict__ Bcnt, const int* __restrict__ Bbase,
    const uint2* __restrict__ ebuf, int* __restrict__ rowstart,
    int* __restrict__ srcl) {
  __shared__ int cnt[BROWS];
  __shared__ int ssum[256];
  const int b = blockIdx.x;
  const int r0 = b * BROWS;
  const int nrows = min(BROWS, NN - r0);
  const int ne = Bcnt[b];
  const int base = Bbase[b];
  const uint2* eb = ebuf + (size_t)b * BCAP;
  const int t = threadIdx.x;

  cnt[2 * t] = (2 * t < nrows) ? 1 : 0;
  cnt[2 * t + 1] = (2 * t + 1 < nrows) ? 1 : 0;
  __syncthreads();
  for (int j = t; j < ne; j += 256)
    atomicAdd(&cnt[(int)eb[j].y - r0], 1);
  __syncthreads();

  int a0 = cnt[2 * t], a1 = cnt[2 * t + 1];
  ssum[t] = a0 + a1;
  __syncthreads();
  for (int off = 1; off < 256; off <<= 1) {
    int u = (t >= off) ? ssum[t - off] : 0;
    __syncthreads();
    ssum[t] += u;
    __syncthreads();
  }
  int e0 = base + ssum[t] - (a0 + a1);
  int e1 = e0 + a0;
  __syncthreads();
  if (2 * t < nrows)     { rowstart[r0 + 2 * t] = e0;     srcl[e0] = r0 + 2 * t; }
  if (2 * t + 1 < nrows) { rowstart[r0 + 2 * t + 1] = e1; srcl[e1] = r0 + 2 * t + 1; }
  cnt[2 * t] = e0 + 1;
  cnt[2 * t + 1] = e1 + 1;
  __syncthreads();
  for (int j = t; j < ne; j += 256) {
    uint2 pr = eb[j];
    int p = atomicAdd(&cnt[(int)pr.y - r0], 1);
    srcl[p] = (int)pr.x;
  }
}

// ---------------- gather: h2[r] = b + sum g[srcl entries] ----------------
// Dual-stream wave: lanes 0-31 = stream A (rows wra..wra+7), lanes 32-63 =
// stream B (rows wra+8..wra+15). One global_load_dword per lane with per-lane
// 64-bit address fetches TWO edges per instruction (row=128B, 4B/lane = cols
// 2q,2q+1). Metadata stays wave-uniform (SGPR srcl loads); per-half row state
// (cur, nb from LDS, acc) is per-lane. 2-deep ping-pong, 16 instr/chunk.
#define RF(x) __builtin_amdgcn_readfirstlane(x)
#define MINI(a, b) ((a) < (b) ? (a) : (b))
#define WAIT16 do { asm volatile("s_waitcnt vmcnt(16)" ::: "memory"); \
    __builtin_amdgcn_sched_barrier(0); } while (0)
#define WAIT0 do { asm volatile("s_waitcnt vmcnt(0)" ::: "memory"); \
    __builtin_amdgcn_sched_barrier(0); } while (0)
#define GLD2(V, IA, IB) do { \
  uint_t _row = (uint_t)(half ? (IB) : (IA)); \
  const uchar_t* _p = g8 + (((size_t)_row) << 7) + boff; \
  asm volatile("global_load_dword %0, %1, off" : "=v"(V) : "v"(_p) : "memory"); \
} while (0)
#define IST(P, K, CA, CB) do { \
  int _ia = RF(srcl[MINI((CA) + (K), eLastA)]); \
  int _ib = RF(srcl[MINI((CB) + (K), eLastB)]); \
  GLD2(P##K, _ia, _ib); \
} while (0)
#define ISSUE16P(P, CA, CB) do { \
  IST(P, 0, CA, CB);  IST(P, 1, CA, CB);  IST(P, 2, CA, CB);  IST(P, 3, CA, CB); \
  IST(P, 4, CA, CB);  IST(P, 5, CA, CB);  IST(P, 6, CA, CB);  IST(P, 7, CA, CB); \
  IST(P, 8, CA, CB);  IST(P, 9, CA, CB);  IST(P, 10, CA, CB); IST(P, 11, CA, CB); \
  IST(P, 12, CA, CB); IST(P, 13, CA, CB); IST(P, 14, CA, CB); IST(P, 15, CA, CB); \
} while (0)
#define FLUSHROW do { \
  uint_t _o = ((uint_t)(ushort_t)f2bf(acc0)) | (((uint_t)(ushort_t)f2bf(acc1)) << 16); \
  *(uint_t*)(h2 + (size_t)cur * HH + 2 * q) = _o; \
  ps0 += acc0; ps1 += acc1; pq0 += acc0 * acc0; pq1 += acc1 * acc1; \
  cur += 1; nb = bnd[wid][cur - wra]; acc0 = bb.x; acc1 = bb.y; \
} while (0)
#define CJ2(V) do { \
  if (ec < eEnd) { \
    if (ec == nb) { FLUSHROW; } \
    acc0 += bf2f(V); acc1 += bfhi(V); \
  } \
  ec += 1; \
} while (0)
#define CONS16P(P) do { \
  CJ2(P##0);  CJ2(P##1);  CJ2(P##2);  CJ2(P##3); \
  CJ2(P##4);  CJ2(P##5);  CJ2(P##6);  CJ2(P##7); \
  CJ2(P##8);  CJ2(P##9);  CJ2(P##10); CJ2(P##11); \
  CJ2(P##12); CJ2(P##13); CJ2(P##14); CJ2(P##15); \
} while (0)

__global__ __launch_bounds__(128) void k_gather(
    const ushort_t* __restrict__ g, const int* __restrict__ rowstart,
    const int* __restrict__ srcl, const float* __restrict__ bias,
    ushort_t* __restrict__ h2, float* __restrict__ stats) {
  __shared__ int bnd[2][16];
  __shared__ float sred[2][128];
  const uchar_t* g8 = (const uchar_t*)g;
  const int lane = threadIdx.x & 63;
  const int wid  = threadIdx.x >> 6;            // 0..1
  const int half = lane >> 5;
  const int q    = lane & 31;
  const uint_t boff = (uint_t)q * 4;
  const int wra = RF((blockIdx.x * 2 + wid) * 16);   // 16 rows per wave; NN%32==0

  int ridx = wra + 1 + lane;                    // boundaries rowstart[wra+1..wra+16]
  if (lane < 16) bnd[wid][lane] = (ridx < NN) ? rowstart[ridx] : NTOT;
  __syncthreads();

  const float2 bb = ((const float2*)bias)[q];
  const int eA0   = RF(rowstart[wra]);
  const int eEndA = RF(bnd[wid][7]);
  const int eEndB = RF(bnd[wid][15]);
  const int eB0   = eEndA;
  const int eLastA = eEndA - 1;
  const int eLastB = eEndB - 1;

  int eEnd = half ? eEndB : eEndA;              // per-lane
  int ec   = half ? eB0 : eA0;                  // per-lane edge cursor (my half)
  int cur  = half ? wra + 8 : wra;              // per-lane current row
  int nb   = bnd[wid][cur - wra];               // per-lane next boundary
  float acc0 = bb.x, acc1 = bb.y;
  float ps0 = 0.f, ps1 = 0.f, pq0 = 0.f, pq1 = 0.f;

  uint_t A0, A1, A2, A3, A4, A5, A6, A7, A8, A9, A10, A11, A12, A13, A14, A15;
  uint_t B0, B1, B2, B3, B4, B5, B6, B7, B8, B9, B10, B11, B12, B13, B14, B15;

  int cA = eA0, cB = eB0;                       // uniform chunk bases
  int nA = (eEndA - eA0 + 15) >> 4;
  int nB = (eEndB - eB0 + 15) >> 4;
  int n = nA > nB ? nA : nB;

  if (n > 0) {
    ISSUE16P(A, cA, cB); cA += 16; cB += 16; n--;
    while (n >= 2) {
      ISSUE16P(B, cA, cB); cA += 16; cB += 16; n--;
      WAIT16; CONS16P(A);
      ISSUE16P(A, cA, cB); cA += 16; cB += 16; n--;
      WAIT16; CONS16P(B);
    }
    if (n == 1) {
      ISSUE16P(B, cA, cB);
      WAIT16; CONS16P(A);
      WAIT0;  CONS16P(B);
    } else {
      WAIT0;  CONS16P(A);
    }
  }
  // final row of each half
  {
    uint_t o = ((uint_t)(ushort_t)f2bf(acc0)) | (((uint_t)(ushort_t)f2bf(acc1)) << 16);
    *(uint_t*)(h2 + (size_t)cur * HH + 2 * q) = o;
    ps0 += acc0; ps1 += acc1; pq0 += acc0 * acc0; pq1 += acc1 * acc1;
  }

  // combine halves (same cols), block reduce, atomics
  ps0 += __shfl_xor(ps0, 32); ps1 += __shfl_xor(ps1, 32);
  pq0 += __shfl_xor(pq0, 32); pq1 += __shfl_xor(pq1, 32);
  if (half == 0) {
    sred[wid][2 * q] = ps0;      sred[wid][2 * q + 1] = ps1;
    sred[wid][64 + 2 * q] = pq0; sred[wid][64 + 2 * q + 1] = pq1;
  }
  __syncthreads();
  if (threadIdx.x < 64) {
    int l = threadIdx.x;
    atomicAdd(&stats[l], sred[0][l] + sred[1][l]);
    atomicAdd(&stats[HH + l], sred[0][64 + l] + sred[1][64 + l]);
  }
}

// ---------------- final: wsi = max0 + max1 ----------------
__global__ void k_wsi(const float* __restrict__ m0, const float* __restrict__ m1,
                      float* __restrict__ out) {
  int i = threadIdx.x;
  out[i] = m0[i] + m1[i];
}

extern "C" void kernel_launch(void* const* d_in, const int* in_sizes, int n_in,
                              void* d_out, int out_size, void* d_ws, size_t ws_size,
                              hipStream_t stream) {
  const float* x    = (const float*)d_in[0];
  const int*   ei   = (const int*)d_in[1];
  const int*   bat  = (const int*)d_in[2];
  const float* Wf   = (const float*)d_in[3];
  const float* bf   = (const float*)d_in[4];
  const float* g1   = (const float*)d_in[5];
  const float* be1  = (const float*)d_in[6];
  const float* Wl0  = (const float*)d_in[7];
  const float* bl0  = (const float*)d_in[8];
  const float* Wc   = (const float*)d_in[9];
  const float* bc   = (const float*)d_in[10];
  const float* g2   = (const float*)d_in[11];
  const float* be2  = (const float*)d_in[12];
  const float* Wl1  = (const float*)d_in[13];
  const float* bl1  = (const float*)d_in[14];

  float* out   = (float*)d_out;
  float* wsi   = out;                 // [8,4]
  float* npred = out + GG * TT;       // [N,4]

  ushort_t* h2bf   = (ushort_t*)d_ws;                 // N*H bf16 (h2)
  ushort_t* h1bf   = h2bf + (size_t)NN * HH;          // N*H bf16 (h1)
  ushort_t* gbf    = h1bf + (size_t)NN * HH;          // N*H bf16 (g)
  float*    stats1 = (float*)(gbf + (size_t)NN * HH); // 256
  float*    stats2 = stats1 + 256;                    // 256
  float*    maxb   = stats2 + 256;                    // 64
  int*      rowstart = (int*)(maxb + 64);             // N
  int*      Bcnt     = rowstart + NN;                 // 256
  int*      Bbase    = Bcnt + 256;                    // 256
  int*      srcl     = Bbase + 256;                   // NE+NN (self-loops)
  uint2*    ebuf     = (uint2*)(srcl + NTOT);         // NBK*BCAP pairs (16 MB)
  ushort_t* Wbf      = (ushort_t*)(ebuf + (size_t)NBK * BCAP);  // DF*HH
  ushort_t* Wbf2     = Wbf + DF * HH;                 // HH*HH

  // setup + bucketed CSR build
  k_setup<<<dim3(80), dim3(256), 0, stream>>>(Wf, Wbf, Wc, Wbf2, stats1, maxb, Bcnt);
  k_part<<<dim3(NPB), dim3(256), 0, stream>>>(ei, Bcnt, ebuf);
  k_bscan<<<dim3(1), dim3(256), 0, stream>>>(Bcnt, Bbase);
  k_fill2<<<dim3(NBK), dim3(256), 0, stream>>>(Bcnt, Bbase, ebuf, rowstart, srcl);

  // Layer 0: GEMM + stats (W in registers — proven config)
  k_gemm1_mfma<<<dim3(512), dim3(256), 0, stream>>>(x, Wbf, bf, h1bf, stats1);
  k_norm_gemm2<<<dim3(512), dim3(256), 0, stream>>>(
      h1bf, stats1, g1, be1, Wl0, bl0, bat, Wbf2, npred, maxb, gbf);

  // Layer 1: h2 = b + g + A.g (dual-stream paired gather)
  k_gather<<<dim3(NN / 32), dim3(128), 0, stream>>>(
      gbf, rowstart, srcl, bc, h2bf, stats2);
  k_norm_np<<<dim3(512), dim3(256), 0, stream>>>(
      h2bf, stats2, g2, be2, Wl1, bl1, bat, npred, maxb + 32, (NN + 511) / 512);

  k_wsi<<<dim3(1), dim3(32), 0, stream>>>(maxb, maxb + 32, wsi);
}

// Round 19
// 293.493 us; speedup vs baseline: 1.0501x; 1.0501x over previous
//
#include <hip/hip_runtime.h>
#include <math.h>

#define NN 100000
#define NE 1600000
#define DF 256
#define HH 64
#define TT 4
#define GG 8
#define BN_EPS 1e-5f
#define NTOT (NE + NN)               // srcl entries incl. self-loops

#define BROWS 512                    // rows per bucket
#define NBK ((NN + BROWS - 1) / BROWS)   // 196
#define BCAP 10240                   // bucket capacity (mean 8192, sigma 90)
#define PCHUNK 1600
#define NPB (NE / PCHUNK)            // 1000

typedef __attribute__((ext_vector_type(8))) short short8v;
typedef __attribute__((ext_vector_type(4))) float f32x4;
typedef unsigned short ushort_t;
typedef unsigned int uint_t;

__device__ __forceinline__ void atomicMaxF(float* addr, float val) {
  if (val >= 0.f) atomicMax((int*)addr, __float_as_int(val));
  else            atomicMin((unsigned int*)addr, __float_as_uint(val));
}

__device__ __forceinline__ short f2bf(float f) {
  uint_t u = __float_as_uint(f);
  u += 0x7FFFu + ((u >> 16) & 1u);
  return (short)(u >> 16);
}
__device__ __forceinline__ float bf2f(uint_t u) { return __uint_as_float(u << 16); }
__device__ __forceinline__ float bfhi(uint_t u) { return __uint_as_float(u & 0xFFFF0000u); }

// ---------------- setup: frag-pack weights (coalesced prologues downstream),
//                  stats=0, maxb=-inf, Bcnt=0 ----------------
// Wpk  [fi=s*4+ct][lane] : W_first B-frags (32 frags)
// Wpk2 [fi=s*4+ct][lane] : W_conv  B-frags (8 frags)
// hpk  [s][lane]         : head B-frags, cols>=TT zeroed (2 frags)
__global__ void k_setup(const float* __restrict__ Wf, const float* __restrict__ Wc,
                        const float* __restrict__ Wl0,
                        short8v* __restrict__ Wpk, short8v* __restrict__ Wpk2,
                        short8v* __restrict__ hpk,
                        float* __restrict__ stats, float* __restrict__ maxb,
                        int* __restrict__ Bcnt) {
  int i = blockIdx.x * 256 + threadIdx.x;       // 11 blocks x 256 = 2816
  if (i < 2048) {
    int fi = i >> 6, le = i & 63;
    int s = fi >> 2, ct = fi & 3, li = le & 15, lh = le >> 4;
    short8v v;
#pragma unroll
    for (int e = 0; e < 8; ++e)
      v[e] = f2bf(Wf[(32 * s + 8 * lh + e) * HH + ct * 16 + li]);
    Wpk[i] = v;
  } else if (i < 2560) {
    int j = i - 2048;
    int fi = j >> 6, le = j & 63;
    int s = fi >> 2, ct = fi & 3, li = le & 15, lh = le >> 4;
    short8v v;
#pragma unroll
    for (int e = 0; e < 8; ++e)
      v[e] = f2bf(Wc[(32 * s + 8 * lh + e) * HH + ct * 16 + li]);
    Wpk2[j] = v;
  } else if (i < 2688) {
    int j = i - 2560;
    int s = j >> 6, le = j & 63;
    int li = le & 15, lh = le >> 4;
    short8v v;
#pragma unroll
    for (int e = 0; e < 8; ++e)
      v[e] = (li < TT) ? f2bf(Wl0[(32 * s + 8 * lh + e) * TT + li]) : (short)0;
    hpk[j] = v;
  }
  if (i < 512) stats[i] = 0.f;
  if (i < 64)  maxb[i]  = -INFINITY;
  if (i < NBK) Bcnt[i]  = 0;
}

// ---------------- GEMM1 (MFMA bf16): h1 = x @ W_first + b (bf16 out), + BN stats ----
// W in registers, loaded via 32 COALESCED short8v reads from frag-packed Wpk
// (old prologue: 256 scattered 2B loads/lane -> compiler-serialized latency chain).
__global__ __launch_bounds__(256, 2) void k_gemm1_mfma(
    const float* __restrict__ x, const short8v* __restrict__ Wpk,
    const float* __restrict__ b, ushort_t* __restrict__ h1,
    float* __restrict__ stats) {
  const int lane = threadIdx.x & 63;
  const int li = lane & 15;
  const int lh = lane >> 4;
  const int gw = (blockIdx.x * 256 + (int)threadIdx.x) >> 6;
  const int nw = (gridDim.x * 256) >> 6;

  short8v bf[8][4];
#pragma unroll
  for (int s = 0; s < 8; ++s)
#pragma unroll
    for (int ct = 0; ct < 4; ++ct)
      bf[s][ct] = Wpk[(s * 4 + ct) * 64 + lane];

  float bias[4];
#pragma unroll
  for (int ct = 0; ct < 4; ++ct) bias[ct] = b[ct * 16 + li];

  float ps[4] = {0.f, 0.f, 0.f, 0.f}, pss[4] = {0.f, 0.f, 0.f, 0.f};

  for (int t = gw; t < NN / 16; t += nw) {
    const float* xb = x + (size_t)(t * 16 + li) * DF + 8 * lh;
    f32x4 acc[4];
#pragma unroll
    for (int ct = 0; ct < 4; ++ct) acc[ct] = (f32x4){0.f, 0.f, 0.f, 0.f};

#pragma unroll
    for (int s = 0; s < 8; ++s) {
      float4 a0 = *(const float4*)(xb + 32 * s);
      float4 a1 = *(const float4*)(xb + 32 * s + 4);
      short8v af;
      af[0] = f2bf(a0.x); af[1] = f2bf(a0.y); af[2] = f2bf(a0.z); af[3] = f2bf(a0.w);
      af[4] = f2bf(a1.x); af[5] = f2bf(a1.y); af[6] = f2bf(a1.z); af[7] = f2bf(a1.w);
#pragma unroll
      for (int ct = 0; ct < 4; ++ct)
        acc[ct] = __builtin_amdgcn_mfma_f32_16x16x32_bf16(af, bf[s][ct], acc[ct], 0, 0, 0);
    }

    ushort_t* hb = h1 + (size_t)t * 16 * HH;
#pragma unroll
    for (int ct = 0; ct < 4; ++ct) {
#pragma unroll
      for (int r = 0; r < 4; ++r) {
        float h = acc[ct][r] + bias[ct];
        hb[(lh * 4 + r) * HH + ct * 16 + li] = (ushort_t)f2bf(h);
        ps[ct] += h; pss[ct] += h * h;
      }
    }
  }

#pragma unroll
  for (int ct = 0; ct < 4; ++ct) {
    ps[ct]  += __shfl_xor(ps[ct], 16);  ps[ct]  += __shfl_xor(ps[ct], 32);
    pss[ct] += __shfl_xor(pss[ct], 16); pss[ct] += __shfl_xor(pss[ct], 32);
  }
  if (lane < 16) {
#pragma unroll
    for (int ct = 0; ct < 4; ++ct) {
      atomicAdd(&stats[ct * 16 + lane], ps[ct]);
      atomicAdd(&stats[HH + ct * 16 + lane], pss[ct]);
    }
  }
}

// ---------------- fused: BN-finalize + normalize(h1)+ReLU; np0 + pool via 5th
//                  MFMA tile; g = f @ W_conv (bf16 out). Coalesced W prologue. ----
__global__ __launch_bounds__(256) void k_norm_gemm2(
    const ushort_t* __restrict__ h1, const float* __restrict__ stats,
    const float* __restrict__ gamma, const float* __restrict__ beta,
    const short8v* __restrict__ Wpk2, const short8v* __restrict__ hpk,
    const float* __restrict__ bl0,
    const int* __restrict__ batch,
    float* __restrict__ node_pred, float* __restrict__ maxbuf,
    ushort_t* __restrict__ g) {
  __shared__ float lmax[GG * TT];
  __shared__ float abl[128];
  if (threadIdx.x < GG * TT) lmax[threadIdx.x] = -INFINITY;
  if (threadIdx.x < 64) {
    int c = threadIdx.x;
    float mu  = stats[c] * (1.f / NN);
    float var = stats[HH + c] * (1.f / NN) - mu * mu;
    float a = gamma[c] * rsqrtf(var + BN_EPS);
    abl[c] = a;
    abl[HH + c] = beta[c] - mu * a;
  }
  __syncthreads();

  const int lane = threadIdx.x & 63;
  const int li = lane & 15;
  const int lh = lane >> 4;
  const int gw = (blockIdx.x * 256 + (int)threadIdx.x) >> 6;
  const int nw = (gridDim.x * 256) >> 6;

  short8v bfr[2][4];
#pragma unroll
  for (int s = 0; s < 2; ++s)
#pragma unroll
    for (int ct = 0; ct < 4; ++ct)
      bfr[s][ct] = Wpk2[(s * 4 + ct) * 64 + lane];

  short8v bhd[2];
#pragma unroll
  for (int s = 0; s < 2; ++s)
    bhd[s] = hpk[s * 64 + lane];

  const float4 sa0 = *(const float4*)(abl + 8 * lh);
  const float4 sa1 = *(const float4*)(abl + 8 * lh + 4);
  const float4 sb0 = *(const float4*)(abl + HH + 8 * lh);
  const float4 sb1 = *(const float4*)(abl + HH + 8 * lh + 4);
  const float4 ta0 = *(const float4*)(abl + 32 + 8 * lh);
  const float4 ta1 = *(const float4*)(abl + 32 + 8 * lh + 4);
  const float4 tb0 = *(const float4*)(abl + HH + 32 + 8 * lh);
  const float4 tb1 = *(const float4*)(abl + HH + 32 + 8 * lh + 4);
  const float blv = (li < TT) ? bl0[li] : 0.f;

  for (int t = gw; t < NN / 16; t += nw) {
    const ushort_t* hb = h1 + (size_t)(t * 16 + li) * HH + 8 * lh;
    uint4 xa = *(const uint4*)(hb);
    uint4 xc = *(const uint4*)(hb + 32);

    short8v af0, af1;
    af0[0] = f2bf(fmaxf(fmaf(sa0.x, bf2f(xa.x), sb0.x), 0.f));
    af0[1] = f2bf(fmaxf(fmaf(sa0.y, bfhi(xa.x), sb0.y), 0.f));
    af0[2] = f2bf(fmaxf(fmaf(sa0.z, bf2f(xa.y), sb0.z), 0.f));
    af0[3] = f2bf(fmaxf(fmaf(sa0.w, bfhi(xa.y), sb0.w), 0.f));
    af0[4] = f2bf(fmaxf(fmaf(sa1.x, bf2f(xa.z), sb1.x), 0.f));
    af0[5] = f2bf(fmaxf(fmaf(sa1.y, bfhi(xa.z), sb1.y), 0.f));
    af0[6] = f2bf(fmaxf(fmaf(sa1.z, bf2f(xa.w), sb1.z), 0.f));
    af0[7] = f2bf(fmaxf(fmaf(sa1.w, bfhi(xa.w), sb1.w), 0.f));
    af1[0] = f2bf(fmaxf(fmaf(ta0.x, bf2f(xc.x), tb0.x), 0.f));
    af1[1] = f2bf(fmaxf(fmaf(ta0.y, bfhi(xc.x), tb0.y), 0.f));
    af1[2] = f2bf(fmaxf(fmaf(ta0.z, bf2f(xc.y), tb0.z), 0.f));
    af1[3] = f2bf(fmaxf(fmaf(ta0.w, bfhi(xc.y), tb0.w), 0.f));
    af1[4] = f2bf(fmaxf(fmaf(ta1.x, bf2f(xc.z), tb1.x), 0.f));
    af1[5] = f2bf(fmaxf(fmaf(ta1.y, bfhi(xc.z), tb1.y), 0.f));
    af1[6] = f2bf(fmaxf(fmaf(ta1.z, bf2f(xc.w), tb1.z), 0.f));
    af1[7] = f2bf(fmaxf(fmaf(ta1.w, bfhi(xc.w), tb1.w), 0.f));

    f32x4 acc[4], acch;
#pragma unroll
    for (int ct = 0; ct < 4; ++ct) {
      acc[ct] = (f32x4){0.f, 0.f, 0.f, 0.f};
      acc[ct] = __builtin_amdgcn_mfma_f32_16x16x32_bf16(af0, bfr[0][ct], acc[ct], 0, 0, 0);
      acc[ct] = __builtin_amdgcn_mfma_f32_16x16x32_bf16(af1, bfr[1][ct], acc[ct], 0, 0, 0);
    }
    acch = (f32x4){0.f, 0.f, 0.f, 0.f};
    acch = __builtin_amdgcn_mfma_f32_16x16x32_bf16(af0, bhd[0], acch, 0, 0, 0);
    acch = __builtin_amdgcn_mfma_f32_16x16x32_bf16(af1, bhd[1], acch, 0, 0, 0);

    ushort_t* gb = g + (size_t)t * 16 * HH;
#pragma unroll
    for (int ct = 0; ct < 4; ++ct)
#pragma unroll
      for (int r = 0; r < 4; ++r)
        gb[(lh * 4 + r) * HH + ct * 16 + li] = (ushort_t)f2bf(acc[ct][r]);

    if (li < TT) {
#pragma unroll
      for (int r = 0; r < 4; ++r) {
        int row = t * 16 + lh * 4 + r;
        float np = acch[r] + blv;
        atomicMaxF(&lmax[batch[row] * TT + li], np);
        node_pred[(size_t)row * TT + li] = np;
      }
    }
  }
  __syncthreads();
  if (threadIdx.x < GG * TT) atomicMaxF(&maxbuf[threadIdx.x], lmax[threadIdx.x]);
}

// ---------------- fused: BN-finalize + normalize+ReLU + head + max-pool ----
__global__ __launch_bounds__(256) void k_norm_np(
    const ushort_t* __restrict__ hin, const float* __restrict__ stats,
    const float* __restrict__ gamma, const float* __restrict__ beta,
    const float* __restrict__ Wlin, const float* __restrict__ blin,
    const int* __restrict__ batch, float* __restrict__ node_pred,
    float* __restrict__ maxbuf, int rpb) {
  __shared__ float lmax[GG * TT];
  __shared__ float abl[128];
  if (threadIdx.x < GG * TT) lmax[threadIdx.x] = -INFINITY;
  if (threadIdx.x < 64) {
    int c = threadIdx.x;
    float mu  = stats[c] * (1.f / NN);
    float var = stats[HH + c] * (1.f / NN) - mu * mu;
    float a = gamma[c] * rsqrtf(var + BN_EPS);
    abl[c] = a;
    abl[HH + c] = beta[c] - mu * a;
  }
  __syncthreads();

  const int lane = threadIdx.x & 63;
  const int wid  = threadIdx.x >> 6;
  const float a  = abl[lane];
  const float b2 = abl[HH + lane];
  const float4 w = ((const float4*)Wlin)[lane];
  const float4 bl = *(const float4*)blin;
  int r0 = blockIdx.x * rpb;
  int r1 = min(r0 + rpb, NN);

  for (int r = r0 + wid; r < r1; r += 4) {
    float h = bf2f(hin[(size_t)r * HH + lane]);
    float f = fmaxf(fmaf(a, h, b2), 0.f);
    float p0 = f * w.x, p1 = f * w.y, p2 = f * w.z, p3 = f * w.w;
#pragma unroll
    for (int off = 32; off; off >>= 1) {
      p0 += __shfl_xor(p0, off);
      p1 += __shfl_xor(p1, off);
      p2 += __shfl_xor(p2, off);
      p3 += __shfl_xor(p3, off);
    }
    if (lane == 0) {
      float4 np;
      np.x = p0 + bl.x; np.y = p1 + bl.y; np.z = p2 + bl.z; np.w = p3 + bl.w;
      int g = batch[r];
      atomicMaxF(&lmax[g * TT + 0], np.x);
      atomicMaxF(&lmax[g * TT + 1], np.y);
      atomicMaxF(&lmax[g * TT + 2], np.z);
      atomicMaxF(&lmax[g * TT + 3], np.w);
      float4* op = (float4*)(node_pred + (size_t)r * TT);
      float4 o = *op;
      np.x += o.x; np.y += o.y; np.z += o.z; np.w += o.w;
      *op = np;
    }
  }
  __syncthreads();
  if (threadIdx.x < GG * TT) atomicMaxF(&maxbuf[threadIdx.x], lmax[threadIdx.x]);
}

// ---------------- bucketed CSR build ----------------
__global__ __launch_bounds__(256) void k_part(
    const int* __restrict__ ei, int* __restrict__ Bcnt,
    uint2* __restrict__ ebuf) {
  __shared__ int hist[256], start[256], cnt[256], gbase[256];
  __shared__ int ssrc[PCHUNK], sdst[PCHUNK];
  const int t = threadIdx.x;
  hist[t] = 0; cnt[t] = 0;
  __syncthreads();
  const int e0 = blockIdx.x * PCHUNK;
  for (int i = t; i < PCHUNK; i += 256)
    atomicAdd(&hist[ei[NE + e0 + i] >> 9], 1);
  __syncthreads();
  int v = hist[t];
  start[t] = v;
  __syncthreads();
  for (int off = 1; off < 256; off <<= 1) {
    int u = (t >= off) ? start[t - off] : 0;
    __syncthreads();
    start[t] += u;
    __syncthreads();
  }
  int incl = start[t];
  __syncthreads();
  start[t] = incl - v;                       // exclusive
  if (v > 0) gbase[t] = atomicAdd(&Bcnt[t], v);
  __syncthreads();
  for (int i = t; i < PCHUNK; i += 256) {
    int src = ei[e0 + i];
    int dst = ei[NE + e0 + i];
    int b = dst >> 9;
    int p = start[b] + atomicAdd(&cnt[b], 1);
    ssrc[p] = src; sdst[p] = dst;
  }
  __syncthreads();
  for (int i = t; i < PCHUNK; i += 256) {
    int dst = sdst[i];
    int b = dst >> 9;
    uint2 pr; pr.x = (uint_t)ssrc[i]; pr.y = (uint_t)dst;
    ebuf[(size_t)b * BCAP + gbase[b] + (i - start[b])] = pr;
  }
}

__global__ void k_bscan(const int* __restrict__ Bcnt, int* __restrict__ Bbase) {
  __shared__ int s[256];
  int t = threadIdx.x;
  int v = 0;
  if (t < NBK) {
    int rows = min(BROWS, NN - t * BROWS);
    v = Bcnt[t] + rows;
  }
  s[t] = v;
  __syncthreads();
  for (int off = 1; off < 256; off <<= 1) {
    int u = (t >= off) ? s[t - off] : 0;
    __syncthreads();
    s[t] += u;
    __syncthreads();
  }
  if (t < NBK) Bbase[t] = s[t] - v;
}

__global__ __launch_bounds__(256) void k_fill2(
    const int* __restrict__ Bcnt, const int* __restrict__ Bbase,
    const uint2* __restrict__ ebuf, int* __restrict__ rowstart,
    int* __restrict__ srcl) {
  __shared__ int cnt[BROWS];
  __shared__ int ssum[256];
  const int b = blockIdx.x;
  const int r0 = b * BROWS;
  const int nrows = min(BROWS, NN - r0);
  const int ne = Bcnt[b];
  const int base = Bbase[b];
  const uint2* eb = ebuf + (size_t)b * BCAP;
  const int t = threadIdx.x;

  cnt[2 * t] = (2 * t < nrows) ? 1 : 0;
  cnt[2 * t + 1] = (2 * t + 1 < nrows) ? 1 : 0;
  __syncthreads();
  for (int j = t; j < ne; j += 256)
    atomicAdd(&cnt[(int)eb[j].y - r0], 1);
  __syncthreads();

  int a0 = cnt[2 * t], a1 = cnt[2 * t + 1];
  ssum[t] = a0 + a1;
  __syncthreads();
  for (int off = 1; off < 256; off <<= 1) {
    int u = (t >= off) ? ssum[t - off] : 0;
    __syncthreads();
    ssum[t] += u;
    __syncthreads();
  }
  int e0 = base + ssum[t] - (a0 + a1);
  int e1 = e0 + a0;
  __syncthreads();
  if (2 * t < nrows)     { rowstart[r0 + 2 * t] = e0;     srcl[e0] = r0 + 2 * t; }
  if (2 * t + 1 < nrows) { rowstart[r0 + 2 * t + 1] = e1; srcl[e1] = r0 + 2 * t + 1; }
  cnt[2 * t] = e0 + 1;
  cnt[2 * t + 1] = e1 + 1;
  __syncthreads();
  for (int j = t; j < ne; j += 256) {
    uint2 pr = eb[j];
    int p = atomicAdd(&cnt[(int)pr.y - r0], 1);
    srcl[p] = (int)pr.x;
  }
}

// ---------------- gather: h2[r] = b + sum_{srcl entries incl self} g[s] ----------------
// R16 proven config: full wave per row (lane=column, bf16), flat edge stream,
// 2-deep ping-pong, 16 loads/chunk, occupancy ~60%.
#define RF(x) __builtin_amdgcn_readfirstlane(x)
#define GLD(V, I) asm volatile("global_load_ushort %0, %1, %2" \
    : "=v"(V) : "v"(voff), "s"(g + (size_t)(I) * HH) : "memory")
#define WAIT16 do { asm volatile("s_waitcnt vmcnt(16)" ::: "memory"); \
    __builtin_amdgcn_sched_barrier(0); } while (0)
#define WAIT0 do { asm volatile("s_waitcnt vmcnt(0)" ::: "memory"); \
    __builtin_amdgcn_sched_barrier(0); } while (0)
#define ISSUE16(P, EB) do { \
  int j0 = RF(srcl[(EB) + 0]),  j1 = RF(srcl[(EB) + 1]); \
  int j2 = RF(srcl[(EB) + 2]),  j3 = RF(srcl[(EB) + 3]); \
  int j4 = RF(srcl[(EB) + 4]),  j5 = RF(srcl[(EB) + 5]); \
  int j6 = RF(srcl[(EB) + 6]),  j7 = RF(srcl[(EB) + 7]); \
  int j8 = RF(srcl[(EB) + 8]),  j9 = RF(srcl[(EB) + 9]); \
  int j10 = RF(srcl[(EB) + 10]), j11 = RF(srcl[(EB) + 11]); \
  int j12 = RF(srcl[(EB) + 12]), j13 = RF(srcl[(EB) + 13]); \
  int j14 = RF(srcl[(EB) + 14]), j15 = RF(srcl[(EB) + 15]); \
  GLD(P##0, j0);  GLD(P##1, j1);  GLD(P##2, j2);  GLD(P##3, j3); \
  GLD(P##4, j4);  GLD(P##5, j5);  GLD(P##6, j6);  GLD(P##7, j7); \
  GLD(P##8, j8);  GLD(P##9, j9);  GLD(P##10, j10); GLD(P##11, j11); \
  GLD(P##12, j12); GLD(P##13, j13); GLD(P##14, j14); GLD(P##15, j15); \
} while (0)
#define CJ(V, EI) do { \
  if ((EI) == nb) { \
    h2[(size_t)cur * HH + lane] = (ushort_t)f2bf(acc); ps += acc; pss += acc * acc; \
    cur++; nb = __builtin_amdgcn_readlane(rsv, cur - wra); acc = bc; \
  } \
  acc += bf2f(V); } while (0)
#define CONS16(P, EB) do { \
  CJ(P##0, (EB) + 0);  CJ(P##1, (EB) + 1);  CJ(P##2, (EB) + 2);  CJ(P##3, (EB) + 3); \
  CJ(P##4, (EB) + 4);  CJ(P##5, (EB) + 5);  CJ(P##6, (EB) + 6);  CJ(P##7, (EB) + 7); \
  CJ(P##8, (EB) + 8);  CJ(P##9, (EB) + 9);  CJ(P##10, (EB) + 10); CJ(P##11, (EB) + 11); \
  CJ(P##12, (EB) + 12); CJ(P##13, (EB) + 13); CJ(P##14, (EB) + 14); CJ(P##15, (EB) + 15); \
} while (0)

__global__ __launch_bounds__(256) void k_gather(
    const ushort_t* __restrict__ g, const int* __restrict__ rowstart,
    const int* __restrict__ srcl, const float* __restrict__ bias,
    ushort_t* __restrict__ h2, float* __restrict__ stats) {
  const int lane = threadIdx.x & 63;
  const int wid  = threadIdx.x >> 6;
  const float bc = bias[lane];
  const uint_t voff = lane * 2;
  const int wra = (blockIdx.x * 4 + wid) * 8;

  int ridx = wra + 1 + lane;
  int rsv = (ridx < NN) ? rowstart[ridx] : NTOT;

  int e    = RF(rowstart[wra]);
  int eEnd = __builtin_amdgcn_readlane(rsv, 7);
  int cur  = wra;
  int nb   = __builtin_amdgcn_readlane(rsv, 0);
  float acc = bc, ps = 0.f, pss = 0.f;

  uint_t A0, A1, A2, A3, A4, A5, A6, A7, A8, A9, A10, A11, A12, A13, A14, A15;
  uint_t B0, B1, B2, B3, B4, B5, B6, B7, B8, B9, B10, B11, B12, B13, B14, B15;

  int n = (eEnd - e) >> 4;
  if (n > 0) {
    int pend = e;
    ISSUE16(A, e); e += 16; n--;
    while (n >= 2) {
      int eb = e;
      ISSUE16(B, e); e += 16; n--;
      WAIT16; CONS16(A, pend); pend = eb;
      int ea = e;
      ISSUE16(A, e); e += 16; n--;
      WAIT16; CONS16(B, pend); pend = ea;
    }
    if (n == 1) {
      int eb = e;
      ISSUE16(B, e); e += 16;
      WAIT16; CONS16(A, pend); pend = eb;
      WAIT0;  CONS16(B, pend);
    } else {
      WAIT0;  CONS16(A, pend);
    }
  }
  for (; e < eEnd; ++e) {
    if (e == nb) {
      h2[(size_t)cur * HH + lane] = (ushort_t)f2bf(acc); ps += acc; pss += acc * acc;
      cur++; nb = __builtin_amdgcn_readlane(rsv, cur - wra); acc = bc;
    }
    int i = RF(srcl[e]);
    acc += bf2f(g[(size_t)i * HH + lane]);
  }
  h2[(size_t)cur * HH + lane] = (ushort_t)f2bf(acc); ps += acc; pss += acc * acc;

  __shared__ float sred[4][128];
  sred[wid][lane] = ps;
  sred[wid][64 + lane] = pss;
  __syncthreads();
  if (wid == 0) {
    float s0 = sred[0][lane] + sred[1][lane] + sred[2][lane] + sred[3][lane];
    float q0 = sred[0][64 + lane] + sred[1][64 + lane] + sred[2][64 + lane] + sred[3][64 + lane];
    atomicAdd(&stats[lane], s0);
    atomicAdd(&stats[HH + lane], q0);
  }
}

// ---------------- final: wsi = max0 + max1 ----------------
__global__ void k_wsi(const float* __restrict__ m0, const float* __restrict__ m1,
                      float* __restrict__ out) {
  int i = threadIdx.x;
  out[i] = m0[i] + m1[i];
}

extern "C" void kernel_launch(void* const* d_in, const int* in_sizes, int n_in,
                              void* d_out, int out_size, void* d_ws, size_t ws_size,
                              hipStream_t stream) {
  const float* x    = (const float*)d_in[0];
  const int*   ei   = (const int*)d_in[1];
  const int*   bat  = (const int*)d_in[2];
  const float* Wf   = (const float*)d_in[3];
  const float* bf   = (const float*)d_in[4];
  const float* g1   = (const float*)d_in[5];
  const float* be1  = (const float*)d_in[6];
  const float* Wl0  = (const float*)d_in[7];
  const float* bl0  = (const float*)d_in[8];
  const float* Wc   = (const float*)d_in[9];
  const float* bc   = (const float*)d_in[10];
  const float* g2   = (const float*)d_in[11];
  const float* be2  = (const float*)d_in[12];
  const float* Wl1  = (const float*)d_in[13];
  const float* bl1  = (const float*)d_in[14];

  float* out   = (float*)d_out;
  float* wsi   = out;                 // [8,4]
  float* npred = out + GG * TT;       // [N,4]

  ushort_t* h2bf   = (ushort_t*)d_ws;                 // N*H bf16 (h2)
  ushort_t* h1bf   = h2bf + (size_t)NN * HH;          // N*H bf16 (h1)
  ushort_t* gbf    = h1bf + (size_t)NN * HH;          // N*H bf16 (g)
  float*    stats1 = (float*)(gbf + (size_t)NN * HH); // 256
  float*    stats2 = stats1 + 256;                    // 256
  float*    maxb   = stats2 + 256;                    // 64
  int*      rowstart = (int*)(maxb + 64);             // N
  int*      Bcnt     = rowstart + NN;                 // 256
  int*      Bbase    = Bcnt + 256;                    // 256
  int*      srcl     = Bbase + 256;                   // NE+NN (self-loops)
  uint2*    ebuf     = (uint2*)(srcl + NTOT);         // NBK*BCAP pairs (16 MB)
  short8v*  Wpk      = (short8v*)(ebuf + (size_t)NBK * BCAP);  // 2048 frags
  short8v*  Wpk2     = Wpk + 2048;                    // 512
  short8v*  hpk      = Wpk2 + 512;                    // 128

  // setup (frag-pack weights) + bucketed CSR build
  k_setup<<<dim3(11), dim3(256), 0, stream>>>(Wf, Wc, Wl0, Wpk, Wpk2, hpk,
                                              stats1, maxb, Bcnt);
  k_part<<<dim3(NPB), dim3(256), 0, stream>>>(ei, Bcnt, ebuf);
  k_bscan<<<dim3(1), dim3(256), 0, stream>>>(Bcnt, Bbase);
  k_fill2<<<dim3(NBK), dim3(256), 0, stream>>>(Bcnt, Bbase, ebuf, rowstart, srcl);

  // Layer 0: GEMM + stats (coalesced frag-packed W prologue)
  k_gemm1_mfma<<<dim3(512), dim3(256), 0, stream>>>(x, Wpk, bf, h1bf, stats1);
  k_norm_gemm2<<<dim3(512), dim3(256), 0, stream>>>(
      h1bf, stats1, g1, be1, Wpk2, hpk, bl0, bat, npred, maxb, gbf);

  // Layer 1: h2 = b + g + A.g (2-deep pipelined flat-stream gather)
  k_gather<<<dim3(NN / 32), dim3(256), 0, stream>>>(
      gbf, rowstart, srcl, bc, h2bf, stats2);
  k_norm_np<<<dim3(512), dim3(256), 0, stream>>>(
      h2bf, stats2, g2, be2, Wl1, bl1, bat, npred, maxb + 32, (NN + 511) / 512);

  k_wsi<<<dim3(1), dim3(32), 0, stream>>>(maxb, maxb + 32, wsi);
}

// Round 20
// 276.972 us; speedup vs baseline: 1.1127x; 1.0596x over previous
//
#include <hip/hip_runtime.h>
#include <math.h>

#define NN 100000
#define NE 1600000
#define DF 256
#define HH 64
#define TT 4
#define GG 8
#define BN_EPS 1e-5f
#define NTOT (NE + NN)               // srcl entries incl. self-loops
#define NTILE (NN / 16)              // 6250
#define NPAIRS 1024                  // 512 blocks x 2 pairs

#define BROWS 512                    // rows per bucket
#define NBK ((NN + BROWS - 1) / BROWS)   // 196
#define BCAP 10240                   // bucket capacity (mean 8192, sigma 90)
#define PCHUNK 1600
#define NPB (NE / PCHUNK)            // 1000

typedef __attribute__((ext_vector_type(8))) short short8v;
typedef __attribute__((ext_vector_type(4))) float f32x4;
typedef unsigned short ushort_t;
typedef unsigned int uint_t;

__device__ __forceinline__ void atomicMaxF(float* addr, float val) {
  if (val >= 0.f) atomicMax((int*)addr, __float_as_int(val));
  else            atomicMin((unsigned int*)addr, __float_as_uint(val));
}

__device__ __forceinline__ short f2bf(float f) {
  uint_t u = __float_as_uint(f);
  u += 0x7FFFu + ((u >> 16) & 1u);
  return (short)(u >> 16);
}
__device__ __forceinline__ float bf2f(uint_t u) { return __uint_as_float(u << 16); }
__device__ __forceinline__ float bfhi(uint_t u) { return __uint_as_float(u & 0xFFFF0000u); }

// ---------------- setup: frag-pack weights, stats=0, maxb=-inf, Bcnt=0 ----------------
__global__ void k_setup(const float* __restrict__ Wf, const float* __restrict__ Wc,
                        const float* __restrict__ Wl0,
                        short8v* __restrict__ Wpk, short8v* __restrict__ Wpk2,
                        short8v* __restrict__ hpk,
                        float* __restrict__ stats, float* __restrict__ maxb,
                        int* __restrict__ Bcnt) {
  int i = blockIdx.x * 256 + threadIdx.x;       // 11 blocks x 256 = 2816
  if (i < 2048) {
    int fi = i >> 6, le = i & 63;
    int s = fi >> 2, ct = fi & 3, li = le & 15, lh = le >> 4;
    short8v v;
#pragma unroll
    for (int e = 0; e < 8; ++e)
      v[e] = f2bf(Wf[(32 * s + 8 * lh + e) * HH + ct * 16 + li]);
    Wpk[i] = v;
  } else if (i < 2560) {
    int j = i - 2048;
    int fi = j >> 6, le = j & 63;
    int s = fi >> 2, ct = fi & 3, li = le & 15, lh = le >> 4;
    short8v v;
#pragma unroll
    for (int e = 0; e < 8; ++e)
      v[e] = f2bf(Wc[(32 * s + 8 * lh + e) * HH + ct * 16 + li]);
    Wpk2[j] = v;
  } else if (i < 2688) {
    int j = i - 2560;
    int s = j >> 6, le = j & 63;
    int li = le & 15, lh = le >> 4;
    short8v v;
#pragma unroll
    for (int e = 0; e < 8; ++e)
      v[e] = (li < TT) ? f2bf(Wl0[(32 * s + 8 * lh + e) * TT + li]) : (short)0;
    hpk[j] = v;
  }
  if (i < 512) stats[i] = 0.f;
  if (i < 64)  maxb[i]  = -INFINITY;
  if (i < NBK) Bcnt[i]  = 0;
}

// ---------------- GEMM1 (MFMA bf16), K-SPLIT: wave pair shares a 16-row tile;
// each wave holds HALF of W (64 VGPRs), computes partials over its K-half,
// exchanges non-owned accs via LDS, finalizes 2 col-tiles. Frees ~64 VGPRs
// for load pipelining and lifts occupancy 2->3-4 waves/SIMD. ----------------
__global__ __launch_bounds__(256, 3) void k_gemm1_mfma(
    const float* __restrict__ x, const short8v* __restrict__ Wpk,
    const float* __restrict__ b, ushort_t* __restrict__ h1,
    float* __restrict__ stats) {
  __shared__ float ex[2][2][64][8];             // 8 KB exchange
  const int lane = threadIdx.x & 63;
  const int wid  = threadIdx.x >> 6;
  const int p    = wid >> 1;                    // pair 0..1
  const int kh   = wid & 1;                     // K-half 0..1
  const int li = lane & 15;
  const int lh = lane >> 4;

  short8v bf[4][4];                             // my K-half's B-frags
#pragma unroll
  for (int ss = 0; ss < 4; ++ss)
#pragma unroll
    for (int ct = 0; ct < 4; ++ct)
      bf[ss][ct] = Wpk[((4 * kh + ss) * 4 + ct) * 64 + lane];

  float bias[2];
#pragma unroll
  for (int j = 0; j < 2; ++j) bias[j] = b[(2 * kh + j) * 16 + li];

  float ps[2] = {0.f, 0.f}, pss[2] = {0.f, 0.f};

  const int t0 = blockIdx.x * 2 + p;
  const int nt = (NTILE + NPAIRS - 1) / NPAIRS; // 7, uniform across waves
  for (int it = 0; it < nt; ++it) {
    int t = t0 + it * NPAIRS;
    bool act = t < NTILE;
    f32x4 acc[4];
#pragma unroll
    for (int ct = 0; ct < 4; ++ct) acc[ct] = (f32x4){0.f, 0.f, 0.f, 0.f};

    if (act) {
      const float* xb = x + (size_t)(t * 16 + li) * DF + 128 * kh + 8 * lh;
#pragma unroll
      for (int ss = 0; ss < 4; ++ss) {
        float4 a0 = *(const float4*)(xb + 32 * ss);
        float4 a1 = *(const float4*)(xb + 32 * ss + 4);
        short8v af;
        af[0] = f2bf(a0.x); af[1] = f2bf(a0.y); af[2] = f2bf(a0.z); af[3] = f2bf(a0.w);
        af[4] = f2bf(a1.x); af[5] = f2bf(a1.y); af[6] = f2bf(a1.z); af[7] = f2bf(a1.w);
#pragma unroll
        for (int ct = 0; ct < 4; ++ct)
          acc[ct] = __builtin_amdgcn_mfma_f32_16x16x32_bf16(af, bf[ss][ct], acc[ct], 0, 0, 0);
      }
      // stage my NON-owned col-tiles (partner owns them)
      int oc = 2 * (1 - kh);
#pragma unroll
      for (int j = 0; j < 2; ++j)
#pragma unroll
        for (int r = 0; r < 4; ++r)
          ex[p][kh][lane][4 * j + r] = acc[oc + j][r];
    }
    __syncthreads();
    if (act) {
      ushort_t* hb = h1 + (size_t)t * 16 * HH;
#pragma unroll
      for (int j = 0; j < 2; ++j) {
        int ct = 2 * kh + j;
#pragma unroll
        for (int r = 0; r < 4; ++r) {
          float h = acc[ct][r] + ex[p][1 - kh][lane][4 * j + r] + bias[j];
          hb[(lh * 4 + r) * HH + ct * 16 + li] = (ushort_t)f2bf(h);
          ps[j] += h; pss[j] += h * h;
        }
      }
    }
    __syncthreads();
  }

#pragma unroll
  for (int j = 0; j < 2; ++j) {
    ps[j]  += __shfl_xor(ps[j], 16);  ps[j]  += __shfl_xor(ps[j], 32);
    pss[j] += __shfl_xor(pss[j], 16); pss[j] += __shfl_xor(pss[j], 32);
  }
  if (lane < 16) {
#pragma unroll
    for (int j = 0; j < 2; ++j) {
      atomicAdd(&stats[(2 * kh + j) * 16 + lane], ps[j]);
      atomicAdd(&stats[HH + (2 * kh + j) * 16 + lane], pss[j]);
    }
  }
}

// ---------------- fused: BN-finalize + normalize(h1)+ReLU; np0 + pool via 5th
//                  MFMA tile; g = f @ W_conv (bf16 out). Coalesced W prologue. ----
__global__ __launch_bounds__(256) void k_norm_gemm2(
    const ushort_t* __restrict__ h1, const float* __restrict__ stats,
    const float* __restrict__ gamma, const float* __restrict__ beta,
    const short8v* __restrict__ Wpk2, const short8v* __restrict__ hpk,
    const float* __restrict__ bl0,
    const int* __restrict__ batch,
    float* __restrict__ node_pred, float* __restrict__ maxbuf,
    ushort_t* __restrict__ g) {
  __shared__ float lmax[GG * TT];
  __shared__ float abl[128];
  if (threadIdx.x < GG * TT) lmax[threadIdx.x] = -INFINITY;
  if (threadIdx.x < 64) {
    int c = threadIdx.x;
    float mu  = stats[c] * (1.f / NN);
    float var = stats[HH + c] * (1.f / NN) - mu * mu;
    float a = gamma[c] * rsqrtf(var + BN_EPS);
    abl[c] = a;
    abl[HH + c] = beta[c] - mu * a;
  }
  __syncthreads();

  const int lane = threadIdx.x & 63;
  const int li = lane & 15;
  const int lh = lane >> 4;
  const int gw = (blockIdx.x * 256 + (int)threadIdx.x) >> 6;
  const int nw = (gridDim.x * 256) >> 6;

  short8v bfr[2][4];
#pragma unroll
  for (int s = 0; s < 2; ++s)
#pragma unroll
    for (int ct = 0; ct < 4; ++ct)
      bfr[s][ct] = Wpk2[(s * 4 + ct) * 64 + lane];

  short8v bhd[2];
#pragma unroll
  for (int s = 0; s < 2; ++s)
    bhd[s] = hpk[s * 64 + lane];

  const float4 sa0 = *(const float4*)(abl + 8 * lh);
  const float4 sa1 = *(const float4*)(abl + 8 * lh + 4);
  const float4 sb0 = *(const float4*)(abl + HH + 8 * lh);
  const float4 sb1 = *(const float4*)(abl + HH + 8 * lh + 4);
  const float4 ta0 = *(const float4*)(abl + 32 + 8 * lh);
  const float4 ta1 = *(const float4*)(abl + 32 + 8 * lh + 4);
  const float4 tb0 = *(const float4*)(abl + HH + 32 + 8 * lh);
  const float4 tb1 = *(const float4*)(abl + HH + 32 + 8 * lh + 4);
  const float blv = (li < TT) ? bl0[li] : 0.f;

  for (int t = gw; t < NN / 16; t += nw) {
    const ushort_t* hb = h1 + (size_t)(t * 16 + li) * HH + 8 * lh;
    uint4 xa = *(const uint4*)(hb);
    uint4 xc = *(const uint4*)(hb + 32);

    short8v af0, af1;
    af0[0] = f2bf(fmaxf(fmaf(sa0.x, bf2f(xa.x), sb0.x), 0.f));
    af0[1] = f2bf(fmaxf(fmaf(sa0.y, bfhi(xa.x), sb0.y), 0.f));
    af0[2] = f2bf(fmaxf(fmaf(sa0.z, bf2f(xa.y), sb0.z), 0.f));
    af0[3] = f2bf(fmaxf(fmaf(sa0.w, bfhi(xa.y), sb0.w), 0.f));
    af0[4] = f2bf(fmaxf(fmaf(sa1.x, bf2f(xa.z), sb1.x), 0.f));
    af0[5] = f2bf(fmaxf(fmaf(sa1.y, bfhi(xa.z), sb1.y), 0.f));
    af0[6] = f2bf(fmaxf(fmaf(sa1.z, bf2f(xa.w), sb1.z), 0.f));
    af0[7] = f2bf(fmaxf(fmaf(sa1.w, bfhi(xa.w), sb1.w), 0.f));
    af1[0] = f2bf(fmaxf(fmaf(ta0.x, bf2f(xc.x), tb0.x), 0.f));
    af1[1] = f2bf(fmaxf(fmaf(ta0.y, bfhi(xc.x), tb0.y), 0.f));
    af1[2] = f2bf(fmaxf(fmaf(ta0.z, bf2f(xc.y), tb0.z), 0.f));
    af1[3] = f2bf(fmaxf(fmaf(ta0.w, bfhi(xc.y), tb0.w), 0.f));
    af1[4] = f2bf(fmaxf(fmaf(ta1.x, bf2f(xc.z), tb1.x), 0.f));
    af1[5] = f2bf(fmaxf(fmaf(ta1.y, bfhi(xc.z), tb1.y), 0.f));
    af1[6] = f2bf(fmaxf(fmaf(ta1.z, bf2f(xc.w), tb1.z), 0.f));
    af1[7] = f2bf(fmaxf(fmaf(ta1.w, bfhi(xc.w), tb1.w), 0.f));

    f32x4 acc[4], acch;
#pragma unroll
    for (int ct = 0; ct < 4; ++ct) {
      acc[ct] = (f32x4){0.f, 0.f, 0.f, 0.f};
      acc[ct] = __builtin_amdgcn_mfma_f32_16x16x32_bf16(af0, bfr[0][ct], acc[ct], 0, 0, 0);
      acc[ct] = __builtin_amdgcn_mfma_f32_16x16x32_bf16(af1, bfr[1][ct], acc[ct], 0, 0, 0);
    }
    acch = (f32x4){0.f, 0.f, 0.f, 0.f};
    acch = __builtin_amdgcn_mfma_f32_16x16x32_bf16(af0, bhd[0], acch, 0, 0, 0);
    acch = __builtin_amdgcn_mfma_f32_16x16x32_bf16(af1, bhd[1], acch, 0, 0, 0);

    ushort_t* gb = g + (size_t)t * 16 * HH;
#pragma unroll
    for (int ct = 0; ct < 4; ++ct)
#pragma unroll
      for (int r = 0; r < 4; ++r)
        gb[(lh * 4 + r) * HH + ct * 16 + li] = (ushort_t)f2bf(acc[ct][r]);

    if (li < TT) {
#pragma unroll
      for (int r = 0; r < 4; ++r) {
        int row = t * 16 + lh * 4 + r;
        float np = acch[r] + blv;
        atomicMaxF(&lmax[batch[row] * TT + li], np);
        node_pred[(size_t)row * TT + li] = np;
      }
    }
  }
  __syncthreads();
  if (threadIdx.x < GG * TT) atomicMaxF(&maxbuf[threadIdx.x], lmax[threadIdx.x]);
}

// ---------------- fused: BN-finalize + normalize+ReLU + head + max-pool ----
__global__ __launch_bounds__(256) void k_norm_np(
    const ushort_t* __restrict__ hin, const float* __restrict__ stats,
    const float* __restrict__ gamma, const float* __restrict__ beta,
    const float* __restrict__ Wlin, const float* __restrict__ blin,
    const int* __restrict__ batch, float* __restrict__ node_pred,
    float* __restrict__ maxbuf, int rpb) {
  __shared__ float lmax[GG * TT];
  __shared__ float abl[128];
  if (threadIdx.x < GG * TT) lmax[threadIdx.x] = -INFINITY;
  if (threadIdx.x < 64) {
    int c = threadIdx.x;
    float mu  = stats[c] * (1.f / NN);
    float var = stats[HH + c] * (1.f / NN) - mu * mu;
    float a = gamma[c] * rsqrtf(var + BN_EPS);
    abl[c] = a;
    abl[HH + c] = beta[c] - mu * a;
  }
  __syncthreads();

  const int lane = threadIdx.x & 63;
  const int wid  = threadIdx.x >> 6;
  const float a  = abl[lane];
  const float b2 = abl[HH + lane];
  const float4 w = ((const float4*)Wlin)[lane];
  const float4 bl = *(const float4*)blin;
  int r0 = blockIdx.x * rpb;
  int r1 = min(r0 + rpb, NN);

  for (int r = r0 + wid; r < r1; r += 4) {
    float h = bf2f(hin[(size_t)r * HH + lane]);
    float f = fmaxf(fmaf(a, h, b2), 0.f);
    float p0 = f * w.x, p1 = f * w.y, p2 = f * w.z, p3 = f * w.w;
#pragma unroll
    for (int off = 32; off; off >>= 1) {
      p0 += __shfl_xor(p0, off);
      p1 += __shfl_xor(p1, off);
      p2 += __shfl_xor(p2, off);
      p3 += __shfl_xor(p3, off);
    }
    if (lane == 0) {
      float4 np;
      np.x = p0 + bl.x; np.y = p1 + bl.y; np.z = p2 + bl.z; np.w = p3 + bl.w;
      int g = batch[r];
      atomicMaxF(&lmax[g * TT + 0], np.x);
      atomicMaxF(&lmax[g * TT + 1], np.y);
      atomicMaxF(&lmax[g * TT + 2], np.z);
      atomicMaxF(&lmax[g * TT + 3], np.w);
      float4* op = (float4*)(node_pred + (size_t)r * TT);
      float4 o = *op;
      np.x += o.x; np.y += o.y; np.z += o.z; np.w += o.w;
      *op = np;
    }
  }
  __syncthreads();
  if (threadIdx.x < GG * TT) atomicMaxF(&maxbuf[threadIdx.x], lmax[threadIdx.x]);
}

// ---------------- bucketed CSR build ----------------
__global__ __launch_bounds__(256) void k_part(
    const int* __restrict__ ei, int* __restrict__ Bcnt,
    uint2* __restrict__ ebuf) {
  __shared__ int hist[256], start[256], cnt[256], gbase[256];
  __shared__ int ssrc[PCHUNK], sdst[PCHUNK];
  const int t = threadIdx.x;
  hist[t] = 0; cnt[t] = 0;
  __syncthreads();
  const int e0 = blockIdx.x * PCHUNK;
  for (int i = t; i < PCHUNK; i += 256)
    atomicAdd(&hist[ei[NE + e0 + i] >> 9], 1);
  __syncthreads();
  int v = hist[t];
  start[t] = v;
  __syncthreads();
  for (int off = 1; off < 256; off <<= 1) {
    int u = (t >= off) ? start[t - off] : 0;
    __syncthreads();
    start[t] += u;
    __syncthreads();
  }
  int incl = start[t];
  __syncthreads();
  start[t] = incl - v;                       // exclusive
  if (v > 0) gbase[t] = atomicAdd(&Bcnt[t], v);
  __syncthreads();
  for (int i = t; i < PCHUNK; i += 256) {
    int src = ei[e0 + i];
    int dst = ei[NE + e0 + i];
    int b = dst >> 9;
    int p = start[b] + atomicAdd(&cnt[b], 1);
    ssrc[p] = src; sdst[p] = dst;
  }
  __syncthreads();
  for (int i = t; i < PCHUNK; i += 256) {
    int dst = sdst[i];
    int b = dst >> 9;
    uint2 pr; pr.x = (uint_t)ssrc[i]; pr.y = (uint_t)dst;
    ebuf[(size_t)b * BCAP + gbase[b] + (i - start[b])] = pr;
  }
}

__global__ void k_bscan(const int* __restrict__ Bcnt, int* __restrict__ Bbase) {
  __shared__ int s[256];
  int t = threadIdx.x;
  int v = 0;
  if (t < NBK) {
    int rows = min(BROWS, NN - t * BROWS);
    v = Bcnt[t] + rows;
  }
  s[t] = v;
  __syncthreads();
  for (int off = 1; off < 256; off <<= 1) {
    int u = (t >= off) ? s[t - off] : 0;
    __syncthreads();
    s[t] += u;
    __syncthreads();
  }
  if (t < NBK) Bbase[t] = s[t] - v;
}

__global__ __launch_bounds__(256) void k_fill2(
    const int* __restrict__ Bcnt, const int* __restrict__ Bbase,
    const uint2* __restrict__ ebuf, int* __restrict__ rowstart,
    int* __restrict__ srcl) {
  __shared__ int cnt[BROWS];
  __shared__ int ssum[256];
  const int b = blockIdx.x;
  const int r0 = b * BROWS;
  const int nrows = min(BROWS, NN - r0);
  const int ne = Bcnt[b];
  const int base = Bbase[b];
  const uint2* eb = ebuf + (size_t)b * BCAP;
  const int t = threadIdx.x;

  cnt[2 * t] = (2 * t < nrows) ? 1 : 0;
  cnt[2 * t + 1] = (2 * t + 1 < nrows) ? 1 : 0;
  __syncthreads();
  for (int j = t; j < ne; j += 256)
    atomicAdd(&cnt[(int)eb[j].y - r0], 1);
  __syncthreads();

  int a0 = cnt[2 * t], a1 = cnt[2 * t + 1];
  ssum[t] = a0 + a1;
  __syncthreads();
  for (int off = 1; off < 256; off <<= 1) {
    int u = (t >= off) ? ssum[t - off] : 0;
    __syncthreads();
    ssum[t] += u;
    __syncthreads();
  }
  int e0 = base + ssum[t] - (a0 + a1);
  int e1 = e0 + a0;
  __syncthreads();
  if (2 * t < nrows)     { rowstart[r0 + 2 * t] = e0;     srcl[e0] = r0 + 2 * t; }
  if (2 * t + 1 < nrows) { rowstart[r0 + 2 * t + 1] = e1; srcl[e1] = r0 + 2 * t + 1; }
  cnt[2 * t] = e0 + 1;
  cnt[2 * t + 1] = e1 + 1;
  __syncthreads();
  for (int j = t; j < ne; j += 256) {
    uint2 pr = eb[j];
    int p = atomicAdd(&cnt[(int)pr.y - r0], 1);
    srcl[p] = (int)pr.x;
  }
}

// ---------------- gather: h2[r] = b + sum_{srcl entries incl self} g[s] ----------------
// R16 proven config: full wave per row (lane=column, bf16), flat edge stream,
// 2-deep ping-pong, 16 loads/chunk, occupancy ~60%.
#define RF(x) __builtin_amdgcn_readfirstlane(x)
#define GLD(V, I) asm volatile("global_load_ushort %0, %1, %2" \
    : "=v"(V) : "v"(voff), "s"(g + (size_t)(I) * HH) : "memory")
#define WAIT16 do { asm volatile("s_waitcnt vmcnt(16)" ::: "memory"); \
    __builtin_amdgcn_sched_barrier(0); } while (0)
#define WAIT0 do { asm volatile("s_waitcnt vmcnt(0)" ::: "memory"); \
    __builtin_amdgcn_sched_barrier(0); } while (0)
#define ISSUE16(P, EB) do { \
  int j0 = RF(srcl[(EB) + 0]),  j1 = RF(srcl[(EB) + 1]); \
  int j2 = RF(srcl[(EB) + 2]),  j3 = RF(srcl[(EB) + 3]); \
  int j4 = RF(srcl[(EB) + 4]),  j5 = RF(srcl[(EB) + 5]); \
  int j6 = RF(srcl[(EB) + 6]),  j7 = RF(srcl[(EB) + 7]); \
  int j8 = RF(srcl[(EB) + 8]),  j9 = RF(srcl[(EB) + 9]); \
  int j10 = RF(srcl[(EB) + 10]), j11 = RF(srcl[(EB) + 11]); \
  int j12 = RF(srcl[(EB) + 12]), j13 = RF(srcl[(EB) + 13]); \
  int j14 = RF(srcl[(EB) + 14]), j15 = RF(srcl[(EB) + 15]); \
  GLD(P##0, j0);  GLD(P##1, j1);  GLD(P##2, j2);  GLD(P##3, j3); \
  GLD(P##4, j4);  GLD(P##5, j5);  GLD(P##6, j6);  GLD(P##7, j7); \
  GLD(P##8, j8);  GLD(P##9, j9);  GLD(P##10, j10); GLD(P##11, j11); \
  GLD(P##12, j12); GLD(P##13, j13); GLD(P##14, j14); GLD(P##15, j15); \
} while (0)
#define CJ(V, EI) do { \
  if ((EI) == nb) { \
    h2[(size_t)cur * HH + lane] = (ushort_t)f2bf(acc); ps += acc; pss += acc * acc; \
    cur++; nb = __builtin_amdgcn_readlane(rsv, cur - wra); acc = bc; \
  } \
  acc += bf2f(V); } while (0)
#define CONS16(P, EB) do { \
  CJ(P##0, (EB) + 0);  CJ(P##1, (EB) + 1);  CJ(P##2, (EB) + 2);  CJ(P##3, (EB) + 3); \
  CJ(P##4, (EB) + 4);  CJ(P##5, (EB) + 5);  CJ(P##6, (EB) + 6);  CJ(P##7, (EB) + 7); \
  CJ(P##8, (EB) + 8);  CJ(P##9, (EB) + 9);  CJ(P##10, (EB) + 10); CJ(P##11, (EB) + 11); \
  CJ(P##12, (EB) + 12); CJ(P##13, (EB) + 13); CJ(P##14, (EB) + 14); CJ(P##15, (EB) + 15); \
} while (0)

__global__ __launch_bounds__(256) void k_gather(
    const ushort_t* __restrict__ g, const int* __restrict__ rowstart,
    const int* __restrict__ srcl, const float* __restrict__ bias,
    ushort_t* __restrict__ h2, float* __restrict__ stats) {
  const int lane = threadIdx.x & 63;
  const int wid  = threadIdx.x >> 6;
  const float bc = bias[lane];
  const uint_t voff = lane * 2;
  const int wra = (blockIdx.x * 4 + wid) * 8;

  int ridx = wra + 1 + lane;
  int rsv = (ridx < NN) ? rowstart[ridx] : NTOT;

  int e    = RF(rowstart[wra]);
  int eEnd = __builtin_amdgcn_readlane(rsv, 7);
  int cur  = wra;
  int nb   = __builtin_amdgcn_readlane(rsv, 0);
  float acc = bc, ps = 0.f, pss = 0.f;

  uint_t A0, A1, A2, A3, A4, A5, A6, A7, A8, A9, A10, A11, A12, A13, A14, A15;
  uint_t B0, B1, B2, B3, B4, B5, B6, B7, B8, B9, B10, B11, B12, B13, B14, B15;

  int n = (eEnd - e) >> 4;
  if (n > 0) {
    int pend = e;
    ISSUE16(A, e); e += 16; n--;
    while (n >= 2) {
      int eb = e;
      ISSUE16(B, e); e += 16; n--;
      WAIT16; CONS16(A, pend); pend = eb;
      int ea = e;
      ISSUE16(A, e); e += 16; n--;
      WAIT16; CONS16(B, pend); pend = ea;
    }
    if (n == 1) {
      int eb = e;
      ISSUE16(B, e); e += 16;
      WAIT16; CONS16(A, pend); pend = eb;
      WAIT0;  CONS16(B, pend);
    } else {
      WAIT0;  CONS16(A, pend);
    }
  }
  for (; e < eEnd; ++e) {
    if (e == nb) {
      h2[(size_t)cur * HH + lane] = (ushort_t)f2bf(acc); ps += acc; pss += acc * acc;
      cur++; nb = __builtin_amdgcn_readlane(rsv, cur - wra); acc = bc;
    }
    int i = RF(srcl[e]);
    acc += bf2f(g[(size_t)i * HH + lane]);
  }
  h2[(size_t)cur * HH + lane] = (ushort_t)f2bf(acc); ps += acc; pss += acc * acc;

  __shared__ float sred[4][128];
  sred[wid][lane] = ps;
  sred[wid][64 + lane] = pss;
  __syncthreads();
  if (wid == 0) {
    float s0 = sred[0][lane] + sred[1][lane] + sred[2][lane] + sred[3][lane];
    float q0 = sred[0][64 + lane] + sred[1][64 + lane] + sred[2][64 + lane] + sred[3][64 + lane];
    atomicAdd(&stats[lane], s0);
    atomicAdd(&stats[HH + lane], q0);
  }
}

// ---------------- final: wsi = max0 + max1 ----------------
__global__ void k_wsi(const float* __restrict__ m0, const float* __restrict__ m1,
                      float* __restrict__ out) {
  int i = threadIdx.x;
  out[i] = m0[i] + m1[i];
}

extern "C" void kernel_launch(void* const* d_in, const int* in_sizes, int n_in,
                              void* d_out, int out_size, void* d_ws, size_t ws_size,
                              hipStream_t stream) {
  const float* x    = (const float*)d_in[0];
  const int*   ei   = (const int*)d_in[1];
  const int*   bat  = (const int*)d_in[2];
  const float* Wf   = (const float*)d_in[3];
  const float* bf   = (const float*)d_in[4];
  const float* g1   = (const float*)d_in[5];
  const float* be1  = (const float*)d_in[6];
  const float* Wl0  = (const float*)d_in[7];
  const float* bl0  = (const float*)d_in[8];
  const float* Wc   = (const float*)d_in[9];
  const float* bc   = (const float*)d_in[10];
  const float* g2   = (const float*)d_in[11];
  const float* be2  = (const float*)d_in[12];
  const float* Wl1  = (const float*)d_in[13];
  const float* bl1  = (const float*)d_in[14];

  float* out   = (float*)d_out;
  float* wsi   = out;                 // [8,4]
  float* npred = out + GG * TT;       // [N,4]

  ushort_t* h2bf   = (ushort_t*)d_ws;                 // N*H bf16 (h2)
  ushort_t* h1bf   = h2bf + (size_t)NN * HH;          // N*H bf16 (h1)
  ushort_t* gbf    = h1bf + (size_t)NN * HH;          // N*H bf16 (g)
  float*    stats1 = (float*)(gbf + (size_t)NN * HH); // 256
  float*    stats2 = stats1 + 256;                    // 256
  float*    maxb   = stats2 + 256;                    // 64
  int*      rowstart = (int*)(maxb + 64);             // N
  int*      Bcnt     = rowstart + NN;                 // 256
  int*      Bbase    = Bcnt + 256;                    // 256
  int*      srcl     = Bbase + 256;                   // NE+NN (self-loops)
  uint2*    ebuf     = (uint2*)(srcl + NTOT);         // NBK*BCAP pairs (16 MB)
  short8v*  Wpk      = (short8v*)(ebuf + (size_t)NBK * BCAP);  // 2048 frags
  short8v*  Wpk2     = Wpk + 2048;                    // 512
  short8v*  hpk      = Wpk2 + 512;                    // 128

  // setup (frag-pack weights) + bucketed CSR build
  k_setup<<<dim3(11), dim3(256), 0, stream>>>(Wf, Wc, Wl0, Wpk, Wpk2, hpk,
                                              stats1, maxb, Bcnt);
  k_part<<<dim3(NPB), dim3(256), 0, stream>>>(ei, Bcnt, ebuf);
  k_bscan<<<dim3(1), dim3(256), 0, stream>>>(Bcnt, Bbase);
  k_fill2<<<dim3(NBK), dim3(256), 0, stream>>>(Bcnt, Bbase, ebuf, rowstart, srcl);

  // Layer 0: K-split GEMM + stats
  k_gemm1_mfma<<<dim3(512), dim3(256), 0, stream>>>(x, Wpk, bf, h1bf, stats1);
  k_norm_gemm2<<<dim3(512), dim3(256), 0, stream>>>(
      h1bf, stats1, g1, be1, Wpk2, hpk, bl0, bat, npred, maxb, gbf);

  // Layer 1: h2 = b + g + A.g (2-deep pipelined flat-stream gather)
  k_gather<<<dim3(NN / 32), dim3(256), 0, stream>>>(
      gbf, rowstart, srcl, bc, h2bf, stats2);
  k_norm_np<<<dim3(512), dim3(256), 0, stream>>>(
      h2bf, stats2, g2, be2, Wl1, bl1, bat, npred, maxb + 32, (NN + 511) / 512);

  k_wsi<<<dim3(1), dim3(32), 0, stream>>>(maxb, maxb + 32, wsi);
}

// Round 22
// 275.191 us; speedup vs baseline: 1.1199x; 1.0065x over previous
//
#include <hip/hip_runtime.h>
#include <math.h>

#define NN 100000
#define NE 1600000
#define DF 256
#define HH 64
#define TT 4
#define GG 8
#define BN_EPS 1e-5f
#define NTOT (NE + NN)               // srcl entries incl. self-loops
#define NTILE (NN / 16)              // 6250
#define NPAIRS 1024                  // 512 blocks x 2 pairs

#define BROWS 512                    // rows per bucket
#define NBK ((NN + BROWS - 1) / BROWS)   // 196
#define BCAP 10240                   // bucket capacity (mean 8192, sigma 90)
#define PCHUNK 1600
#define NPB (NE / PCHUNK)            // 1000

typedef __attribute__((ext_vector_type(8))) short short8v;
typedef __attribute__((ext_vector_type(4))) float f32x4;
typedef unsigned short ushort_t;
typedef unsigned int uint_t;

__device__ __forceinline__ void atomicMaxF(float* addr, float val) {
  if (val >= 0.f) atomicMax((int*)addr, __float_as_int(val));
  else            atomicMin((unsigned int*)addr, __float_as_uint(val));
}

__device__ __forceinline__ short f2bf(float f) {
  uint_t u = __float_as_uint(f);
  u += 0x7FFFu + ((u >> 16) & 1u);
  return (short)(u >> 16);
}
__device__ __forceinline__ float bf2f(uint_t u) { return __uint_as_float(u << 16); }
__device__ __forceinline__ float bfhi(uint_t u) { return __uint_as_float(u & 0xFFFF0000u); }

// ---------------- setup: frag-pack weights, stats=0, maxb=-inf, Bcnt=0 ----------------
__global__ void k_setup(const float* __restrict__ Wf, const float* __restrict__ Wc,
                        const float* __restrict__ Wl0,
                        short8v* __restrict__ Wpk, short8v* __restrict__ Wpk2,
                        short8v* __restrict__ hpk,
                        float* __restrict__ stats, float* __restrict__ maxb,
                        int* __restrict__ Bcnt) {
  int i = blockIdx.x * 256 + threadIdx.x;       // 11 blocks x 256 = 2816
  if (i < 2048) {
    int fi = i >> 6, le = i & 63;
    int s = fi >> 2, ct = fi & 3, li = le & 15, lh = le >> 4;
    short8v v;
#pragma unroll
    for (int e = 0; e < 8; ++e)
      v[e] = f2bf(Wf[(32 * s + 8 * lh + e) * HH + ct * 16 + li]);
    Wpk[i] = v;
  } else if (i < 2560) {
    int j = i - 2048;
    int fi = j >> 6, le = j & 63;
    int s = fi >> 2, ct = fi & 3, li = le & 15, lh = le >> 4;
    short8v v;
#pragma unroll
    for (int e = 0; e < 8; ++e)
      v[e] = f2bf(Wc[(32 * s + 8 * lh + e) * HH + ct * 16 + li]);
    Wpk2[j] = v;
  } else if (i < 2688) {
    int j = i - 2560;
    int s = j >> 6, le = j & 63;
    int li = le & 15, lh = le >> 4;
    short8v v;
#pragma unroll
    for (int e = 0; e < 8; ++e)
      v[e] = (li < TT) ? f2bf(Wl0[(32 * s + 8 * lh + e) * TT + li]) : (short)0;
    hpk[j] = v;
  }
  if (i < 512) stats[i] = 0.f;
  if (i < 64)  maxb[i]  = -INFINITY;
  if (i < NBK) Bcnt[i]  = 0;
}

// ---------------- GEMM1 (MFMA bf16), K-SPLIT (R20 proven config) ----------------
__global__ __launch_bounds__(256, 3) void k_gemm1_mfma(
    const float* __restrict__ x, const short8v* __restrict__ Wpk,
    const float* __restrict__ b, ushort_t* __restrict__ h1,
    float* __restrict__ stats) {
  __shared__ float ex[2][2][64][8];             // 8 KB exchange
  const int lane = threadIdx.x & 63;
  const int wid  = threadIdx.x >> 6;
  const int p    = wid >> 1;                    // pair 0..1
  const int kh   = wid & 1;                     // K-half 0..1
  const int li = lane & 15;
  const int lh = lane >> 4;

  short8v bf[4][4];
#pragma unroll
  for (int ss = 0; ss < 4; ++ss)
#pragma unroll
    for (int ct = 0; ct < 4; ++ct)
      bf[ss][ct] = Wpk[((4 * kh + ss) * 4 + ct) * 64 + lane];

  float bias[2];
#pragma unroll
  for (int j = 0; j < 2; ++j) bias[j] = b[(2 * kh + j) * 16 + li];

  float ps[2] = {0.f, 0.f}, pss[2] = {0.f, 0.f};

  const int t0 = blockIdx.x * 2 + p;
  const int nt = (NTILE + NPAIRS - 1) / NPAIRS; // 7, uniform
  for (int it = 0; it < nt; ++it) {
    int t = t0 + it * NPAIRS;
    bool act = t < NTILE;
    f32x4 acc[4];
#pragma unroll
    for (int ct = 0; ct < 4; ++ct) acc[ct] = (f32x4){0.f, 0.f, 0.f, 0.f};

    if (act) {
      const float* xb = x + (size_t)(t * 16 + li) * DF + 128 * kh + 8 * lh;
#pragma unroll
      for (int ss = 0; ss < 4; ++ss) {
        float4 a0 = *(const float4*)(xb + 32 * ss);
        float4 a1 = *(const float4*)(xb + 32 * ss + 4);
        short8v af;
        af[0] = f2bf(a0.x); af[1] = f2bf(a0.y); af[2] = f2bf(a0.z); af[3] = f2bf(a0.w);
        af[4] = f2bf(a1.x); af[5] = f2bf(a1.y); af[6] = f2bf(a1.z); af[7] = f2bf(a1.w);
#pragma unroll
        for (int ct = 0; ct < 4; ++ct)
          acc[ct] = __builtin_amdgcn_mfma_f32_16x16x32_bf16(af, bf[ss][ct], acc[ct], 0, 0, 0);
      }
      int oc = 2 * (1 - kh);
#pragma unroll
      for (int j = 0; j < 2; ++j)
#pragma unroll
        for (int r = 0; r < 4; ++r)
          ex[p][kh][lane][4 * j + r] = acc[oc + j][r];
    }
    __syncthreads();
    if (act) {
      ushort_t* hb = h1 + (size_t)t * 16 * HH;
#pragma unroll
      for (int j = 0; j < 2; ++j) {
        int ct = 2 * kh + j;
#pragma unroll
        for (int r = 0; r < 4; ++r) {
          float h = acc[ct][r] + ex[p][1 - kh][lane][4 * j + r] + bias[j];
          hb[(lh * 4 + r) * HH + ct * 16 + li] = (ushort_t)f2bf(h);
          ps[j] += h; pss[j] += h * h;
        }
      }
    }
    __syncthreads();
  }

#pragma unroll
  for (int j = 0; j < 2; ++j) {
    ps[j]  += __shfl_xor(ps[j], 16);  ps[j]  += __shfl_xor(ps[j], 32);
    pss[j] += __shfl_xor(pss[j], 16); pss[j] += __shfl_xor(pss[j], 32);
  }
  if (lane < 16) {
#pragma unroll
    for (int j = 0; j < 2; ++j) {
      atomicAdd(&stats[(2 * kh + j) * 16 + lane], ps[j]);
      atomicAdd(&stats[HH + (2 * kh + j) * 16 + lane], pss[j]);
    }
  }
}

// ---------------- fused: BN-finalize + normalize(h1)+ReLU; np0 + pool via 5th
//                  MFMA tile; g = f @ W_conv (bf16 out) ----------------
__global__ __launch_bounds__(256) void k_norm_gemm2(
    const ushort_t* __restrict__ h1, const float* __restrict__ stats,
    const float* __restrict__ gamma, const float* __restrict__ beta,
    const short8v* __restrict__ Wpk2, const short8v* __restrict__ hpk,
    const float* __restrict__ bl0,
    const int* __restrict__ batch,
    float* __restrict__ node_pred, float* __restrict__ maxbuf,
    ushort_t* __restrict__ g) {
  __shared__ float lmax[GG * TT];
  __shared__ float abl[128];
  if (threadIdx.x < GG * TT) lmax[threadIdx.x] = -INFINITY;
  if (threadIdx.x < 64) {
    int c = threadIdx.x;
    float mu  = stats[c] * (1.f / NN);
    float var = stats[HH + c] * (1.f / NN) - mu * mu;
    float a = gamma[c] * rsqrtf(var + BN_EPS);
    abl[c] = a;
    abl[HH + c] = beta[c] - mu * a;
  }
  __syncthreads();

  const int lane = threadIdx.x & 63;
  const int li = lane & 15;
  const int lh = lane >> 4;
  const int gw = (blockIdx.x * 256 + (int)threadIdx.x) >> 6;
  const int nw = (gridDim.x * 256) >> 6;

  short8v bfr[2][4];
#pragma unroll
  for (int s = 0; s < 2; ++s)
#pragma unroll
    for (int ct = 0; ct < 4; ++ct)
      bfr[s][ct] = Wpk2[(s * 4 + ct) * 64 + lane];

  short8v bhd[2];
#pragma unroll
  for (int s = 0; s < 2; ++s)
    bhd[s] = hpk[s * 64 + lane];

  const float4 sa0 = *(const float4*)(abl + 8 * lh);
  const float4 sa1 = *(const float4*)(abl + 8 * lh + 4);
  const float4 sb0 = *(const float4*)(abl + HH + 8 * lh);
  const float4 sb1 = *(const float4*)(abl + HH + 8 * lh + 4);
  const float4 ta0 = *(const float4*)(abl + 32 + 8 * lh);
  const float4 ta1 = *(const float4*)(abl + 32 + 8 * lh + 4);
  const float4 tb0 = *(const float4*)(abl + HH + 32 + 8 * lh);
  const float4 tb1 = *(const float4*)(abl + HH + 32 + 8 * lh + 4);
  const float blv = (li < TT) ? bl0[li] : 0.f;

  for (int t = gw; t < NN / 16; t += nw) {
    const ushort_t* hb = h1 + (size_t)(t * 16 + li) * HH + 8 * lh;
    uint4 xa = *(const uint4*)(hb);
    uint4 xc = *(const uint4*)(hb + 32);

    short8v af0, af1;
    af0[0] = f2bf(fmaxf(fmaf(sa0.x, bf2f(xa.x), sb0.x), 0.f));
    af0[1] = f2bf(fmaxf(fmaf(sa0.y, bfhi(xa.x), sb0.y), 0.f));
    af0[2] = f2bf(fmaxf(fmaf(sa0.z, bf2f(xa.y), sb0.z), 0.f));
    af0[3] = f2bf(fmaxf(fmaf(sa0.w, bfhi(xa.y), sb0.w), 0.f));
    af0[4] = f2bf(fmaxf(fmaf(sa1.x, bf2f(xa.z), sb1.x), 0.f));
    af0[5] = f2bf(fmaxf(fmaf(sa1.y, bfhi(xa.z), sb1.y), 0.f));
    af0[6] = f2bf(fmaxf(fmaf(sa1.z, bf2f(xa.w), sb1.z), 0.f));
    af0[7] = f2bf(fmaxf(fmaf(sa1.w, bfhi(xa.w), sb1.w), 0.f));
    af1[0] = f2bf(fmaxf(fmaf(ta0.x, bf2f(xc.x), tb0.x), 0.f));
    af1[1] = f2bf(fmaxf(fmaf(ta0.y, bfhi(xc.x), tb0.y), 0.f));
    af1[2] = f2bf(fmaxf(fmaf(ta0.z, bf2f(xc.y), tb0.z), 0.f));
    af1[3] = f2bf(fmaxf(fmaf(ta0.w, bfhi(xc.y), tb0.w), 0.f));
    af1[4] = f2bf(fmaxf(fmaf(ta1.x, bf2f(xc.z), tb1.x), 0.f));
    af1[5] = f2bf(fmaxf(fmaf(ta1.y, bfhi(xc.z), tb1.y), 0.f));
    af1[6] = f2bf(fmaxf(fmaf(ta1.z, bf2f(xc.w), tb1.z), 0.f));
    af1[7] = f2bf(fmaxf(fmaf(ta1.w, bfhi(xc.w), tb1.w), 0.f));

    f32x4 acc[4], acch;
#pragma unroll
    for (int ct = 0; ct < 4; ++ct) {
      acc[ct] = (f32x4){0.f, 0.f, 0.f, 0.f};
      acc[ct] = __builtin_amdgcn_mfma_f32_16x16x32_bf16(af0, bfr[0][ct], acc[ct], 0, 0, 0);
      acc[ct] = __builtin_amdgcn_mfma_f32_16x16x32_bf16(af1, bfr[1][ct], acc[ct], 0, 0, 0);
    }
    acch = (f32x4){0.f, 0.f, 0.f, 0.f};
    acch = __builtin_amdgcn_mfma_f32_16x16x32_bf16(af0, bhd[0], acch, 0, 0, 0);
    acch = __builtin_amdgcn_mfma_f32_16x16x32_bf16(af1, bhd[1], acch, 0, 0, 0);

    ushort_t* gb = g + (size_t)t * 16 * HH;
#pragma unroll
    for (int ct = 0; ct < 4; ++ct)
#pragma unroll
      for (int r = 0; r < 4; ++r)
        gb[(lh * 4 + r) * HH + ct * 16 + li] = (ushort_t)f2bf(acc[ct][r]);

    if (li < TT) {
#pragma unroll
      for (int r = 0; r < 4; ++r) {
        int row = t * 16 + lh * 4 + r;
        float np = acch[r] + blv;
        atomicMaxF(&lmax[batch[row] * TT + li], np);
        node_pred[(size_t)row * TT + li] = np;
      }
    }
  }
  __syncthreads();
  if (threadIdx.x < GG * TT) atomicMaxF(&maxbuf[threadIdx.x], lmax[threadIdx.x]);
}

// ---------------- fused: BN-finalize + normalize+ReLU + head + max-pool ----
__global__ __launch_bounds__(256) void k_norm_np(
    const ushort_t* __restrict__ hin, const float* __restrict__ stats,
    const float* __restrict__ gamma, const float* __restrict__ beta,
    const float* __restrict__ Wlin, const float* __restrict__ blin,
    const int* __restrict__ batch, float* __restrict__ node_pred,
    float* __restrict__ maxbuf, int rpb) {
  __shared__ float lmax[GG * TT];
  __shared__ float abl[128];
  if (threadIdx.x < GG * TT) lmax[threadIdx.x] = -INFINITY;
  if (threadIdx.x < 64) {
    int c = threadIdx.x;
    float mu  = stats[c] * (1.f / NN);
    float var = stats[HH + c] * (1.f / NN) - mu * mu;
    float a = gamma[c] * rsqrtf(var + BN_EPS);
    abl[c] = a;
    abl[HH + c] = beta[c] - mu * a;
  }
  __syncthreads();

  const int lane = threadIdx.x & 63;
  const int wid  = threadIdx.x >> 6;
  const float a  = abl[lane];
  const float b2 = abl[HH + lane];
  const float4 w = ((const float4*)Wlin)[lane];
  const float4 bl = *(const float4*)blin;
  int r0 = blockIdx.x * rpb;
  int r1 = min(r0 + rpb, NN);

  for (int r = r0 + wid; r < r1; r += 4) {
    float h = bf2f(hin[(size_t)r * HH + lane]);
    float f = fmaxf(fmaf(a, h, b2), 0.f);
    float p0 = f * w.x, p1 = f * w.y, p2 = f * w.z, p3 = f * w.w;
#pragma unroll
    for (int off = 32; off; off >>= 1) {
      p0 += __shfl_xor(p0, off);
      p1 += __shfl_xor(p1, off);
      p2 += __shfl_xor(p2, off);
      p3 += __shfl_xor(p3, off);
    }
    if (lane == 0) {
      float4 np;
      np.x = p0 + bl.x; np.y = p1 + bl.y; np.z = p2 + bl.z; np.w = p3 + bl.w;
      int g = batch[r];
      atomicMaxF(&lmax[g * TT + 0], np.x);
      atomicMaxF(&lmax[g * TT + 1], np.y);
      atomicMaxF(&lmax[g * TT + 2], np.z);
      atomicMaxF(&lmax[g * TT + 3], np.w);
      float4* op = (float4*)(node_pred + (size_t)r * TT);
      float4 o = *op;
      np.x += o.x; np.y += o.y; np.z += o.z; np.w += o.w;
      *op = np;
    }
  }
  __syncthreads();
  if (threadIdx.x < GG * TT) atomicMaxF(&maxbuf[threadIdx.x], lmax[threadIdx.x]);
}

// ---------------- bucketed CSR build ----------------
__global__ __launch_bounds__(256) void k_part(
    const int* __restrict__ ei, int* __restrict__ Bcnt,
    uint2* __restrict__ ebuf) {
  __shared__ int hist[256], start[256], cnt[256], gbase[256];
  __shared__ int ssrc[PCHUNK], sdst[PCHUNK];
  const int t = threadIdx.x;
  hist[t] = 0; cnt[t] = 0;
  __syncthreads();
  const int e0 = blockIdx.x * PCHUNK;
  for (int i = t; i < PCHUNK; i += 256)
    atomicAdd(&hist[ei[NE + e0 + i] >> 9], 1);
  __syncthreads();
  int v = hist[t];
  start[t] = v;
  __syncthreads();
  for (int off = 1; off < 256; off <<= 1) {
    int u = (t >= off) ? start[t - off] : 0;
    __syncthreads();
    start[t] += u;
    __syncthreads();
  }
  int incl = start[t];
  __syncthreads();
  start[t] = incl - v;                       // exclusive
  if (v > 0) gbase[t] = atomicAdd(&Bcnt[t], v);
  __syncthreads();
  for (int i = t; i < PCHUNK; i += 256) {
    int src = ei[e0 + i];
    int dst = ei[NE + e0 + i];
    int b = dst >> 9;
    int p = start[b] + atomicAdd(&cnt[b], 1);
    ssrc[p] = src; sdst[p] = dst;
  }
  __syncthreads();
  for (int i = t; i < PCHUNK; i += 256) {
    int dst = sdst[i];
    int b = dst >> 9;
    uint2 pr; pr.x = (uint_t)ssrc[i]; pr.y = (uint_t)dst;
    ebuf[(size_t)b * BCAP + gbase[b] + (i - start[b])] = pr;
  }
}

// k_fill2 with inline base computation (bscan merged: base = r0 + sum Bcnt[<b])
__global__ __launch_bounds__(256) void k_fill2(
    const int* __restrict__ Bcnt, const uint2* __restrict__ ebuf,
    int* __restrict__ rowstart, int* __restrict__ srcl) {
  __shared__ int cnt[BROWS];
  __shared__ int ssum[256];
  const int b = blockIdx.x;
  const int r0 = b * BROWS;
  const int nrows = min(BROWS, NN - r0);
  const int ne = Bcnt[b];
  const uint2* eb = ebuf + (size_t)b * BCAP;
  const int t = threadIdx.x;

  int partial = 0;
  for (int i = t; i < b; i += 256) partial += Bcnt[i];
  ssum[t] = partial;
  __syncthreads();
  for (int off = 128; off; off >>= 1) {
    if (t < off) ssum[t] += ssum[t + off];
    __syncthreads();
  }
  const int base = ssum[0] + r0;
  __syncthreads();

  cnt[2 * t] = (2 * t < nrows) ? 1 : 0;
  cnt[2 * t + 1] = (2 * t + 1 < nrows) ? 1 : 0;
  __syncthreads();
  for (int j = t; j < ne; j += 256)
    atomicAdd(&cnt[(int)eb[j].y - r0], 1);
  __syncthreads();

  int a0 = cnt[2 * t], a1 = cnt[2 * t + 1];
  ssum[t] = a0 + a1;
  __syncthreads();
  for (int off = 1; off < 256; off <<= 1) {
    int u = (t >= off) ? ssum[t - off] : 0;
    __syncthreads();
    ssum[t] += u;
    __syncthreads();
  }
  int e0 = base + ssum[t] - (a0 + a1);
  int e1 = e0 + a0;
  __syncthreads();
  if (2 * t < nrows)     { rowstart[r0 + 2 * t] = e0;     srcl[e0] = r0 + 2 * t; }
  if (2 * t + 1 < nrows) { rowstart[r0 + 2 * t + 1] = e1; srcl[e1] = r0 + 2 * t + 1; }
  cnt[2 * t] = e0 + 1;
  cnt[2 * t + 1] = e1 + 1;
  __syncthreads();
  for (int j = t; j < ne; j += 256) {
    uint2 pr = eb[j];
    int p = atomicAdd(&cnt[(int)pr.y - r0], 1);
    srcl[p] = (int)pr.x;
  }
}

// ---------------- gather: h2[r] = b + sum_{srcl entries incl self} g[s] ----------------
// R16 proven config: full wave per row (lane=column, bf16), flat edge stream,
// 2-deep ping-pong, 16 loads/chunk, occupancy ~60%.
#define RF(x) __builtin_amdgcn_readfirstlane(x)
#define GLD(V, I) asm volatile("global_load_ushort %0, %1, %2" \
    : "=v"(V) : "v"(voff), "s"(g + (size_t)(I) * HH) : "memory")
#define WAIT16 do { asm volatile("s_waitcnt vmcnt(16)" ::: "memory"); \
    __builtin_amdgcn_sched_barrier(0); } while (0)
#define WAIT0 do { asm volatile("s_waitcnt vmcnt(0)" ::: "memory"); \
    __builtin_amdgcn_sched_barrier(0); } while (0)
#define ISSUE16(P, EB) do { \
  int j0 = RF(srcl[(EB) + 0]),  j1 = RF(srcl[(EB) + 1]); \
  int j2 = RF(srcl[(EB) + 2]),  j3 = RF(srcl[(EB) + 3]); \
  int j4 = RF(srcl[(EB) + 4]),  j5 = RF(srcl[(EB) + 5]); \
  int j6 = RF(srcl[(EB) + 6]),  j7 = RF(srcl[(EB) + 7]); \
  int j8 = RF(srcl[(EB) + 8]),  j9 = RF(srcl[(EB) + 9]); \
  int j10 = RF(srcl[(EB) + 10]), j11 = RF(srcl[(EB) + 11]); \
  int j12 = RF(srcl[(EB) + 12]), j13 = RF(srcl[(EB) + 13]); \
  int j14 = RF(srcl[(EB) + 14]), j15 = RF(srcl[(EB) + 15]); \
  GLD(P##0, j0);  GLD(P##1, j1);  GLD(P##2, j2);  GLD(P##3, j3); \
  GLD(P##4, j4);  GLD(P##5, j5);  GLD(P##6, j6);  GLD(P##7, j7); \
  GLD(P##8, j8);  GLD(P##9, j9);  GLD(P##10, j10); GLD(P##11, j11); \
  GLD(P##12, j12); GLD(P##13, j13); GLD(P##14, j14); GLD(P##15, j15); \
} while (0)
#define CJ(V, EI) do { \
  if ((EI) == nb) { \
    h2[(size_t)cur * HH + lane] = (ushort_t)f2bf(acc); ps += acc; pss += acc * acc; \
    cur++; nb = __builtin_amdgcn_readlane(rsv, cur - wra); acc = bc; \
  } \
  acc += bf2f(V); } while (0)
#define CONS16(P, EB) do { \
  CJ(P##0, (EB) + 0);  CJ(P##1, (EB) + 1);  CJ(P##2, (EB) + 2);  CJ(P##3, (EB) + 3); \
  CJ(P##4, (EB) + 4);  CJ(P##5, (EB) + 5);  CJ(P##6, (EB) + 6);  CJ(P##7, (EB) + 7); \
  CJ(P##8, (EB) + 8);  CJ(P##9, (EB) + 9);  CJ(P##10, (EB) + 10); CJ(P##11, (EB) + 11); \
  CJ(P##12, (EB) + 12); CJ(P##13, (EB) + 13); CJ(P##14, (EB) + 14); CJ(P##15, (EB) + 15); \
} while (0)

__global__ __launch_bounds__(256) void k_gather(
    const ushort_t* __restrict__ g, const int* __restrict__ rowstart,
    const int* __restrict__ srcl, const float* __restrict__ bias,
    ushort_t* __restrict__ h2, float* __restrict__ stats) {
  const int lane = threadIdx.x & 63;
  const int wid  = threadIdx.x >> 6;
  const float bc = bias[lane];
  const uint_t voff = lane * 2;
  const int wra = (blockIdx.x * 4 + wid) * 8;

  int ridx = wra + 1 + lane;
  int rsv = (ridx < NN) ? rowstart[ridx] : NTOT;

  int e    = RF(rowstart[wra]);
  int eEnd = __builtin_amdgcn_readlane(rsv, 7);
  int cur  = wra;
  int nb   = __builtin_amdgcn_readlane(rsv, 0);
  float acc = bc, ps = 0.f, pss = 0.f;

  uint_t A0, A1, A2, A3, A4, A5, A6, A7, A8, A9, A10, A11, A12, A13, A14, A15;
  uint_t B0, B1, B2, B3, B4, B5, B6, B7, B8, B9, B10, B11, B12, B13, B14, B15;

  int n = (eEnd - e) >> 4;
  if (n > 0) {
    int pend = e;
    ISSUE16(A, e); e += 16; n--;
    while (n >= 2) {
      int eb = e;
      ISSUE16(B, e); e += 16; n--;
      WAIT16; CONS16(A, pend); pend = eb;
      int ea = e;
      ISSUE16(A, e); e += 16; n--;
      WAIT16; CONS16(B, pend); pend = ea;
    }
    if (n == 1) {
      int eb = e;
      ISSUE16(B, e); e += 16;
      WAIT16; CONS16(A, pend); pend = eb;
      WAIT0;  CONS16(B, pend);
    } else {
      WAIT0;  CONS16(A, pend);
    }
  }
  for (; e < eEnd; ++e) {
    if (e == nb) {
      h2[(size_t)cur * HH + lane] = (ushort_t)f2bf(acc); ps += acc; pss += acc * acc;
      cur++; nb = __builtin_amdgcn_readlane(rsv, cur - wra); acc = bc;
    }
    int i = RF(srcl[e]);
    acc += bf2f(g[(size_t)i * HH + lane]);
  }
  h2[(size_t)cur * HH + lane] = (ushort_t)f2bf(acc); ps += acc; pss += acc * acc;

  __shared__ float sred[4][128];
  sred[wid][lane] = ps;
  sred[wid][64 + lane] = pss;
  __syncthreads();
  if (wid == 0) {
    float s0 = sred[0][lane] + sred[1][lane] + sred[2][lane] + sred[3][lane];
    float q0 = sred[0][64 + lane] + sred[1][64 + lane] + sred[2][64 + lane] + sred[3][64 + lane];
    atomicAdd(&stats[lane], s0);
    atomicAdd(&stats[HH + lane], q0);
  }
}

// ---------------- final: wsi = max0 + max1 ----------------
__global__ void k_wsi(const float* __restrict__ m0, const float* __restrict__ m1,
                      float* __restrict__ out) {
  int i = threadIdx.x;
  out[i] = m0[i] + m1[i];
}

extern "C" void kernel_launch(void* const* d_in, const int* in_sizes, int n_in,
                              void* d_out, int out_size, void* d_ws, size_t ws_size,
                              hipStream_t stream) {
  const float* x    = (const float*)d_in[0];
  const int*   ei   = (const int*)d_in[1];
  const int*   bat  = (const int*)d_in[2];
  const float* Wf   = (const float*)d_in[3];
  const float* bf   = (const float*)d_in[4];
  const float* g1   = (const float*)d_in[5];
  const float* be1  = (const float*)d_in[6];
  const float* Wl0  = (const float*)d_in[7];
  const float* bl0  = (const float*)d_in[8];
  const float* Wc   = (const float*)d_in[9];
  const float* bc   = (const float*)d_in[10];
  const float* g2   = (const float*)d_in[11];
  const float* be2  = (const float*)d_in[12];
  const float* Wl1  = (const float*)d_in[13];
  const float* bl1  = (const float*)d_in[14];

  float* out   = (float*)d_out;
  float* wsi   = out;                 // [8,4]
  float* npred = out + GG * TT;       // [N,4]

  ushort_t* h2bf   = (ushort_t*)d_ws;                 // N*H bf16 (h2)
  ushort_t* h1bf   = h2bf + (size_t)NN * HH;          // N*H bf16 (h1)
  ushort_t* gbf    = h1bf + (size_t)NN * HH;          // N*H bf16 (g)
  float*    stats1 = (float*)(gbf + (size_t)NN * HH); // 256
  float*    stats2 = stats1 + 256;                    // 256
  float*    maxb   = stats2 + 256;                    // 64
  int*      rowstart = (int*)(maxb + 64);             // N
  int*      Bcnt     = rowstart + NN;                 // 256
  int*      srcl     = Bcnt + 256;                    // NE+NN (self-loops)
  uint2*    ebuf     = (uint2*)(srcl + NTOT);         // NBK*BCAP pairs (16 MB)
  short8v*  Wpk      = (short8v*)(ebuf + (size_t)NBK * BCAP);  // 2048 frags
  short8v*  Wpk2     = Wpk + 2048;                    // 512
  short8v*  hpk      = Wpk2 + 512;                    // 128

  // setup (frag-pack weights) + bucketed CSR build (bscan merged into fill2)
  k_setup<<<dim3(11), dim3(256), 0, stream>>>(Wf, Wc, Wl0, Wpk, Wpk2, hpk,
                                              stats1, maxb, Bcnt);
  k_part<<<dim3(NPB), dim3(256), 0, stream>>>(ei, Bcnt, ebuf);
  k_fill2<<<dim3(NBK), dim3(256), 0, stream>>>(Bcnt, ebuf, rowstart, srcl);

  // Layer 0: K-split GEMM + stats
  k_gemm1_mfma<<<dim3(512), dim3(256), 0, stream>>>(x, Wpk, bf, h1bf, stats1);
  k_norm_gemm2<<<dim3(512), dim3(256), 0, stream>>>(
      h1bf, stats1, g1, be1, Wpk2, hpk, bl0, bat, npred, maxb, gbf);

  // Layer 1: h2 = b + g + A.g (2-deep pipelined flat-stream gather)
  k_gather<<<dim3(NN / 32), dim3(256), 0, stream>>>(
      gbf, rowstart, srcl, bc, h2bf, stats2);
  k_norm_np<<<dim3(512), dim3(256), 0, stream>>>(
      h2bf, stats2, g2, be2, Wl1, bl1, bat, npred, maxb + 32, (NN + 511) / 512);

  k_wsi<<<dim3(1), dim3(32), 0, stream>>>(maxb, maxb + 32, wsi);
}